// Round 10
// baseline (332.221 us; speedup 1.0000x reference)
//
#include <hip/hip_runtime.h>

#define EPS 1e-5f

typedef short sh8 __attribute__((ext_vector_type(8)));    // 8 x bf16 (4 VGPR)
typedef float f32x4 __attribute__((ext_vector_type(4)));  // MFMA acc frag

__device__ __forceinline__ ushort f2b(float f) {
    unsigned u = __float_as_uint(f);
    u += 0x7fffu + ((u >> 16) & 1u);          // RNE
    return (ushort)(u >> 16);
}

// ====== InstanceNorm stats body: single-pass f64 (deterministic, stable) =======
__device__ __forceinline__ void istat_body(int ch, const float* __restrict__ in,
                                           float* st, int HW)
{
    __shared__ double sh[512];
    const float* p = in + (size_t)ch * HW;
    double s = 0.0, s2 = 0.0;
    for (int i = threadIdx.x * 4; i < HW; i += 1024) {
        float4 v = *(const float4*)(p + i);
        s  += (double)v.x + (double)v.y + (double)v.z + (double)v.w;
        s2 += (double)v.x * v.x + (double)v.y * v.y
            + (double)v.z * v.z + (double)v.w * v.w;
    }
    sh[threadIdx.x] = s; sh[256 + threadIdx.x] = s2;
    __syncthreads();
    for (int o = 128; o > 0; o >>= 1) {
        if ((int)threadIdx.x < o) {
            sh[threadIdx.x]       += sh[threadIdx.x + o];
            sh[256 + threadIdx.x] += sh[256 + threadIdx.x + o];
        }
        __syncthreads();
    }
    if (threadIdx.x == 0) {
        double m = sh[0] / (double)HW;
        double v = sh[256] / (double)HW - m * m;
        st[2 * ch]     = (float)m;
        st[2 * ch + 1] = (float)(v < 0.0 ? 0.0 : v);
    }
}

// ====== fused inorm-apply (mode0) + padded NHWC bf16 stage body ================
__device__ __forceinline__ void ipad_body(int bxi, int b,
    const float* __restrict__ in, const float* __restrict__ st,
    ushort* __restrict__ ob, int C, int H, int W, int pad, int n4)
{
    int idx = bxi * 256 + threadIdx.x;
    if (idx >= n4) return;
    int cpp = C >> 2;
    int pp = idx / cpp, c0 = (idx - pp * cpp) * 4;
    int Wp = W + 2 * pad, Hp = H + 2 * pad;
    int yp = pp / Wp, xp = pp - yp * Wp;
    int y = yp - pad, x = xp - pad;
    ushort4 o;
    if (y >= 0 && y < H && x >= 0 && x < W) {
        size_t HW = (size_t)H * W;
        const float* ib = in + (size_t)b * C * HW + (size_t)y * W + x;
        #pragma unroll
        for (int u = 0; u < 4; u++) {
            int chg = b * C + c0 + u;
            float m = st[2 * chg];
            float inv = rsqrtf(st[2 * chg + 1] + EPS);
            float v = ib[(size_t)(c0 + u) * HW];
            ((ushort*)&o)[u] = f2b((v - m) * inv);
        }
    } else { o.x = o.y = o.z = o.w = 0; }
    *(ushort4*)(ob + ((size_t)b * Hp * Wp + pp) * C + c0) = o;
}

// ====== plain NCHW f32 -> (padded) NHWC bf16 body ==============================
__device__ __forceinline__ void pad_body(int bxi, int b,
    const float* __restrict__ in, ushort* __restrict__ ob,
    int C, int H, int W, int pad, int n4)
{
    int idx = bxi * 256 + threadIdx.x;
    if (idx >= n4) return;
    int cpp = C >> 2;
    int pp = idx / cpp, c0 = (idx - pp * cpp) * 4;
    int Wp = W + 2 * pad, Hp = H + 2 * pad;
    int yp = pp / Wp, xp = pp - yp * Wp;
    int y = yp - pad, x = xp - pad;
    ushort4 o;
    if (y >= 0 && y < H && x >= 0 && x < W) {
        const float* ib = in + ((size_t)b * C) * H * W + (size_t)y * W + x;
        size_t HW = (size_t)H * W;
        o.x = f2b(ib[(size_t)(c0    ) * HW]);
        o.y = f2b(ib[(size_t)(c0 + 1) * HW]);
        o.z = f2b(ib[(size_t)(c0 + 2) * HW]);
        o.w = f2b(ib[(size_t)(c0 + 3) * HW]);
    } else { o.x = o.y = o.z = o.w = 0; }
    *(ushort4*)(ob + ((size_t)b * Hp * Wp + pp) * C + c0) = o;
}

// ====== fused weight prep body (all bf16 layers) ===============================
__device__ __forceinline__ void wprep_body(int bxi,
    const float* W16, const float* W20, const float* Wd, const float* Wa2,
    const float* Wa1,
    ushort* wT1b, ushort* wT2b, ushort* wbD, ushort* wbA2b, ushort* wbA1b)
{
    int idx = bxi * 256 + threadIdx.x;
    if (idx < 73728) {                       // wT1b: convT (128,64) -> [t*64+o][ci]
        int to = idx / 128, ci = idx - to * 128;
        int t = to / 64, o = to - t * 64;
        wT1b[idx] = f2b(W16[((size_t)ci * 64 + o) * 9 + t]);
        return;
    } idx -= 73728;
    if (idx < 18432) {                       // wT2b: convT (64,32)
        int to = idx / 64, ci = idx - to * 64;
        int t = to / 32, o = to - t * 32;
        wT2b[idx] = f2b(W20[((size_t)ci * 32 + o) * 9 + t]);
        return;
    } idx -= 18432;
    if (idx < 294912) {                      // wbD: OIHW(128,256) -> [co][t][ci]
        int co = idx / 2304, r = idx - co * 2304;
        int t = r / 256, ci = r - t * 256;
        wbD[idx] = f2b(Wd[((size_t)co * 256 + ci) * 9 + t]);
        return;
    } idx -= 294912;
    if (idx < 73728) {                       // wbA2b: OIHW(128,64)
        int co = idx / 576, r = idx - co * 576;
        int t = r / 64, ci = r - t * 64;
        wbA2b[idx] = f2b(Wa2[((size_t)co * 64 + ci) * 9 + t]);
        return;
    } idx -= 73728;
    if (idx < 18432) {                       // wbA1b: OIHW(64,32)
        int co = idx / 288, r = idx - co * 288;
        int t = r / 32, ci = r - t * 32;
        wbA1b[idx] = f2b(Wa1[((size_t)co * 32 + ci) * 9 + t]);
        return;
    }
}

// ====== MFMA GEMM v8: 64px/wave (4 px-groups), chunked B-LDS, A prefetch-2 =====
// block: 256 px x 32 n (4 waves, each 64px x 32n). KCH 32-ch chunks per slice,
// CPB chunks staged per barrier round. LDS = 32 * (TAPS*CPB*32 + 8) ushorts.
template<int CI, int TAPS, int KCH, int CPB>
__device__ __forceinline__ void mg2f_body(int bx, int by, int bz,
    const ushort* __restrict__ inb, const ushort* __restrict__ wb,
    const float* __restrict__ bias, float* __restrict__ outp,
    int wshift, int Wp, int NS, size_t SS,
    size_t in_bstride, size_t out_bstride, int HW, ushort* bsm)
{
    constexpr int CPBSH = (CPB == 1) ? 0 : (CPB == 2) ? 1 : 2;
    constexpr int SPR   = TAPS * CPB;          // steps per round
    constexpr int TOT   = TAPS * KCH;          // k-steps per slice
    constexpr int PS    = SPR * 32 + 8;        // LDS row stride (2-way free)

    int b = bz / NS, sl = bz - b * NS;
    int cilo = sl * (KCH * 32);
    int tid = threadIdx.x;
    int wv = tid >> 6, l = tid & 63;
    int lane16 = l & 15, quad = l >> 4;
    int klane = quad * 8;
    int pb = bx * 256 + wv * 64;
    int nb0 = by * 32;

    int base[4];
    #pragma unroll
    for (int i = 0; i < 4; i++) {
        int pm = pb + i * 16 + lane16;
        if (TAPS == 9) {
            int W = 1 << wshift;
            int y = pm >> wshift, xx = pm & (W - 1);
            base[i] = (y + 1) * Wp + (xx + 1);
        } else base[i] = pm;
    }
    int nn[2];
    nn[0] = nb0 + lane16; nn[1] = nb0 + 16 + lane16;

    const ushort* inbb = inb + (size_t)b * in_bstride + cilo + klane;
    const ushort* wbs  = wb + cilo;
    const ushort* bp0 = bsm + lane16 * PS + klane;
    const ushort* bp1 = bsm + (16 + lane16) * PS + klane;

    f32x4 vz = {0.f, 0.f, 0.f, 0.f};
    f32x4 acc[4][2] = {{vz, vz}, {vz, vz}, {vz, vz}, {vz, vz}};
    sh8 A[3][4];

    #define LDA(ss, av) { \
        int r_ = (ss) / SPR; int l_ = (ss) - r_ * SPR; \
        int t_ = l_ >> CPBSH; int ch_ = r_ * CPB + (l_ & (CPB - 1)); \
        int dof_ = 0; \
        if (TAPS == 9) { \
            int dy_ = (t_ * 43) >> 7; \
            int dx_ = t_ - dy_ * 3; \
            dof_ = (dy_ - 1) * Wp + (dx_ - 1); \
        } \
        int coff_ = ch_ << 5; \
        av[0] = *(const sh8*)(inbb + (size_t)(base[0] + dof_) * CI + coff_); \
        av[1] = *(const sh8*)(inbb + (size_t)(base[1] + dof_) * CI + coff_); \
        av[2] = *(const sh8*)(inbb + (size_t)(base[2] + dof_) * CI + coff_); \
        av[3] = *(const sh8*)(inbb + (size_t)(base[3] + dof_) * CI + coff_); \
    }

    LDA(0, A[0])
    if (TOT > 1) LDA(1, A[1])

    #pragma unroll
    for (int r = 0; r < KCH / CPB; r++) {
        if (r) __syncthreads();
        // ---- stage B round r: 32 n x SPR kchunks x 32 ch ----
        {
            constexpr int elems = 32 * SPR * 4;
            for (int j = tid; j < elems; j += 256) {
                int n  = j / (SPR * 4);
                int rr = j - n * (SPR * 4);
                int kc = rr >> 2, c8 = rr & 3;
                int t_ = kc >> CPBSH, co = kc & (CPB - 1);
                int ch_ = r * CPB + co;
                sh8 v = *(const sh8*)(wbs
                    + ((size_t)(nb0 + n) * TAPS + t_) * CI + (ch_ << 5) + (c8 << 3));
                *(sh8*)(bsm + n * PS + (kc << 5) + (c8 << 3)) = v;
            }
        }
        __syncthreads();
        #pragma unroll
        for (int li = 0; li < SPR; li++) {
            const int s = r * SPR + li;
            if (s + 2 < TOT) LDA(s + 2, A[(s + 2) % 3])
            sh8 b0 = *(const sh8*)(bp0 + (li << 5));
            sh8 b1 = *(const sh8*)(bp1 + (li << 5));
            #pragma unroll
            for (int i = 0; i < 4; i++) {
                acc[i][0] = __builtin_amdgcn_mfma_f32_16x16x32_bf16(A[s % 3][i], b0, acc[i][0], 0, 0, 0);
                acc[i][1] = __builtin_amdgcn_mfma_f32_16x16x32_bf16(A[s % 3][i], b1, acc[i][1], 0, 0, 0);
            }
        }
    }
    #undef LDA

    float* ob = outp + (size_t)sl * SS + (size_t)b * out_bstride;
    #pragma unroll
    for (int j = 0; j < 2; j++) {
        float bb = bias ? bias[nn[j]] : 0.f;
        #pragma unroll
        for (int i = 0; i < 4; i++) {
            int p0 = pb + i * 16 + quad * 4;
            *(float4*)(ob + (size_t)nn[j] * HW + p0) =
                make_float4(acc[i][j][0] + bb, acc[i][j][1] + bb,
                            acc[i][j][2] + bb, acc[i][j][3] + bb);
        }
    }
}

// ====== PAC gaussian, float4-vectorized (NS=1: fused exp; else partial) ========
__device__ __forceinline__ void pack4_body(int bxi, int zy,
    const float* __restrict__ g, float* __restrict__ part,
    int Cg, int CS, int H, int W, int NS, size_t SS)
{
    int b = zy / NS, sl = zy - b * NS;
    int WC = W >> 2;
    int idx = bxi * 256 + threadIdx.x;
    int y = idx / WC, xc = idx - y * WC;
    int x0 = xc << 2;
    bool lz = (x0 == 0), rz = (x0 + 4 == W);
    float acc[9][4];
    #pragma unroll
    for (int t = 0; t < 9; t++)
        #pragma unroll
        for (int p = 0; p < 4; p++) acc[t][p] = 0.f;

    const float* gb = g + ((size_t)b * Cg + sl * CS) * H * W;
    for (int ci = 0; ci < CS; ci++) {
        const float* gc = gb + (size_t)ci * H * W;
        float e[3][6];
        #pragma unroll
        for (int r = 0; r < 3; r++) {
            int yy = y + r - 1;
            float4 v = make_float4(0.f, 0.f, 0.f, 0.f);
            if (yy >= 0 && yy < H)
                v = *(const float4*)(gc + (size_t)yy * W + x0);
            float lf = __shfl_up(v.w, 1);
            float rt = __shfl_down(v.x, 1);
            e[r][0] = lz ? 0.f : lf;
            e[r][1] = v.x; e[r][2] = v.y; e[r][3] = v.z; e[r][4] = v.w;
            e[r][5] = rz ? 0.f : rt;
        }
        #pragma unroll
        for (int i = 0; i < 3; i++)
            #pragma unroll
            for (int j = 0; j < 3; j++)
                #pragma unroll
                for (int p = 0; p < 4; p++) {
                    float d = e[i][p + j] - e[1][p + 1];
                    acc[i * 3 + j][p] = fmaf(d, d, acc[i * 3 + j][p]);
                }
    }
    size_t HW = (size_t)H * W;
    #pragma unroll
    for (int t = 0; t < 9; t++) {
        float4 o;
        if (NS == 1) {
            o = make_float4(expf(-0.5f * acc[t][0]), expf(-0.5f * acc[t][1]),
                            expf(-0.5f * acc[t][2]), expf(-0.5f * acc[t][3]));
        } else {
            o = make_float4(acc[t][0], acc[t][1], acc[t][2], acc[t][3]);
        }
        *(float4*)(part + (size_t)sl * SS + ((size_t)b * 9 + t) * HW
                   + (size_t)y * W + x0) = o;
    }
}

// ====== reduce partials body (+bias) ===========================================
__device__ __forceinline__ void reduce_body(int bxi,
    const float* __restrict__ part, const float* __restrict__ bias,
    const float* res, float* out, int HW, int Co, int NS, size_t SS)
{
    int i4 = (bxi * 256 + threadIdx.x) * 4;
    float4 a = make_float4(0.f, 0.f, 0.f, 0.f);
    for (int s = 0; s < NS; s++) {
        float4 p = *(const float4*)(part + (size_t)s * SS + i4);
        a.x += p.x; a.y += p.y; a.z += p.z; a.w += p.w;
    }
    int c = (i4 / HW) % Co;
    float bb = bias[c];
    if (res) {
        float4 r = *(const float4*)(res + i4);
        a.x += r.x; a.y += r.y; a.z += r.z; a.w += r.w;
    }
    *(float4*)(out + i4) = make_float4(a.x + bb, a.y + bb, a.z + bb, a.w + bb);
}

__device__ __forceinline__ void expcomb_body(int bxi,
    const float* __restrict__ part, float* __restrict__ K, int NS, size_t SS)
{
    int i4 = (bxi * 256 + threadIdx.x) * 4;
    float4 a = make_float4(0.f, 0.f, 0.f, 0.f);
    for (int s = 0; s < NS; s++) {
        float4 p = *(const float4*)(part + (size_t)s * SS + i4);
        a.x += p.x; a.y += p.y; a.z += p.z; a.w += p.w;
    }
    *(float4*)(K + i4) = make_float4(expf(-0.5f * a.x), expf(-0.5f * a.y),
                                     expf(-0.5f * a.z), expf(-0.5f * a.w));
}

// ================= MEGA KERNELS (dependency-depth fusion) ======================
// L0: wprep(1872) | istat x(512) | pad ef2(2114) | pad ef1(4162)  = 8660 blocks
__global__ __launch_bounds__(256) void pro_k(
    const float* x, const float* ef2, const float* ef1,
    const float* W16, const float* W20, const float* Wd, const float* Wa2,
    const float* Wa1,
    ushort* wT1b, ushort* wT2b, ushort* wbD, ushort* wbA2b, ushort* wbA1b,
    float* st0, ushort* padA2b, ushort* padA1b)
{
    int bid = blockIdx.x;
    if (bid < 1872) {
        wprep_body(bid, W16, W20, Wd, Wa2, Wa1, wT1b, wT2b, wbD, wbA2b, wbA1b);
        return;
    } bid -= 1872;
    if (bid < 512) { istat_body(bid, x, st0, 4096); return; } bid -= 512;
    if (bid < 2114) {
        pad_body(bid % 1057, bid / 1057, ef2, padA2b, 64, 128, 128, 1, 270400);
        return;
    } bid -= 2114;
    pad_body(bid % 2081, bid / 2081, ef1, padA1b, 32, 256, 256, 1, 532512);
}

// L1: ipad x(2178) | adj_lv2 full-K(512) | adj_lv1 full-K(1024)  = 3714 blocks
__global__ __launch_bounds__(256) void l1_k(
    const float* x, const float* st0, ushort* padDb,
    const ushort* padA2b, const ushort* wbA2b, const float* ba2, float* g2,
    const ushort* padA1b, const ushort* wbA1b, const float* ba1, float* g1)
{
    __shared__ ushort smem[32 * (9 * 32 + 8)];   // 18944 B
    int bid = blockIdx.x;
    if (bid < 2178) {
        ipad_body(bid % 1089, bid / 1089, x, st0, padDb, 256, 64, 64, 1, 278784);
        return;
    } bid -= 2178;
    if (bid < 512) {    // adj_lv2 64->128 @128x128: K=576, 2 rounds (64x4x2)
        mg2f_body<64, 9, 2, 1>(bid & 63, (bid >> 6) & 3, bid >> 8,
            padA2b, wbA2b, ba2, g2, 7, 130, 1, (size_t)0,
            (size_t)1081600, (size_t)2097152, 16384, smem);
        return;
    } bid -= 512;
    // adj_lv1 32->64 @256x256: K=288, 1 round (256x2x2)
    mg2f_body<32, 9, 1, 1>(bid & 255, (bid >> 8) & 1, bid >> 9,
        padA1b, wbA1b, ba1, g1, 8, 258, 1, (size_t)0,
        (size_t)2130048, (size_t)4194304, 65536, smem);
}

// L2: packK1 NS=4(512) | packK2 NS=8(256) | conv_down NS=8(1024) = 1792 blocks
// (long-chain pack blocks FIRST so the drain tail is the short GEMM blocks)
__global__ __launch_bounds__(256) void l2_k(
    const ushort* padDb, const ushort* wbD, float* Pd,
    const float* g1, float* PK1, const float* g2, float* PK2)
{
    __shared__ ushort smem[32 * (9 * 32 + 8)];   // 18944 B
    int bid = blockIdx.x;
    if (bid < 512) {    // PAC K1 partials NS=4, CS=16
        pack4_body(bid & 63, bid >> 6, g1, PK1, 64, 16, 256, 256, 4, (size_t)1179648);
        return;
    } bid -= 512;
    if (bid < 256) {    // PAC K2 partials NS=8, CS=16
        pack4_body(bid & 15, bid >> 4, g2, PK2, 128, 16, 128, 128, 8, (size_t)294912);
        return;
    } bid -= 256;
    // conv_down 256->128 @64x64: 32ch slice, totk=9 (16x4x16)
    mg2f_body<256, 9, 1, 1>(bid & 15, (bid >> 4) & 3, bid >> 6,
        padDb, wbD, nullptr, Pd, 6, 66, 8, (size_t)1048576,
        (size_t)1115136, (size_t)524288, 4096, smem);
}

// L3: zero STA | reduce Pd(1024) | expcomb K1(1152) | expcomb K2(288) = 2464
__global__ __launch_bounds__(256) void l3_k(
    const float* Pd, const float* bd, float* x1,
    const float* PK1, float* K1, const float* PK2, float* K2, double* sta)
{
    int bid = blockIdx.x;
    if (bid == 0) {
        for (int t = threadIdx.x; t < 384; t += 256) sta[t] = 0.0;
    }
    if (bid < 1024) {
        reduce_body(bid, Pd, bd, nullptr, x1, 4096, 128, 8, (size_t)1048576);
        return;
    } bid -= 1024;
    if (bid < 1152) {
        expcomb_body(bid, PK1, K1, 4, (size_t)1179648);
        return;
    } bid -= 1152;
    expcomb_body(bid, PK2, K2, 8, (size_t)294912);
}

// ================= fused 1x1 conv: full-K + bias + residual -> bf16 NHWC =======
// NCO=4, grid (4,32,2) = 256 blocks
__global__ __launch_bounds__(256) void conv1x1f_k(
    const float* __restrict__ x1, const float* __restrict__ Wm,
    const float* __restrict__ bm, ushort* __restrict__ x2b)
{
    __shared__ float wsm[512];                   // 4 co x 128 ci
    int b = blockIdx.z;
    int co0 = blockIdx.y * 4;
    int tid = threadIdx.x;
    for (int j = tid; j < 512; j += 256) {
        int co = j >> 7, ci = j & 127;
        wsm[j] = Wm[(size_t)(co0 + co) * 128 + ci];
    }
    __syncthreads();
    int px0 = (blockIdx.x * 256 + tid) * 4;
    const float* ib = x1 + (size_t)b * 524288 + px0;
    float acc[4][4];
    #pragma unroll
    for (int j = 0; j < 4; j++)
        #pragma unroll
        for (int p = 0; p < 4; p++) acc[j][p] = 0.f;
    for (int ci = 0; ci < 128; ci++) {
        float4 v = *(const float4*)(ib + (size_t)ci * 4096);
        #pragma unroll
        for (int j = 0; j < 4; j++) {
            float wv = wsm[j * 128 + ci];        // wave-uniform broadcast
            acc[j][0] = fmaf(v.x, wv, acc[j][0]);
            acc[j][1] = fmaf(v.y, wv, acc[j][1]);
            acc[j][2] = fmaf(v.z, wv, acc[j][2]);
            acc[j][3] = fmaf(v.w, wv, acc[j][3]);
        }
    }
    float vals[4][4];
    #pragma unroll
    for (int j = 0; j < 4; j++) {
        float4 r = *(const float4*)(ib + (size_t)(co0 + j) * 4096);
        float bb = bm[co0 + j];
        vals[0][j] = acc[j][0] + r.x + bb;
        vals[1][j] = acc[j][1] + r.y + bb;
        vals[2][j] = acc[j][2] + r.z + bb;
        vals[3][j] = acc[j][3] + r.w + bb;
    }
    #pragma unroll
    for (int p = 0; p < 4; p++) {
        ushort4 ov;
        ov.x = f2b(vals[p][0]); ov.y = f2b(vals[p][1]);
        ov.z = f2b(vals[p][2]); ov.w = f2b(vals[p][3]);
        *(ushort4*)(x2b + ((size_t)b * 4096 + px0 + p) * 128 + co0) = ov;
    }
}

// ================= thin wrappers for the serial tail ===========================
template<int CI, int TAPS, int KCH, int CPB>
__global__ __launch_bounds__(256) void mg2f_k(
    const ushort* __restrict__ inb, const ushort* __restrict__ wb,
    const float* __restrict__ bias, float* __restrict__ outp,
    int wshift, int Wp, int NS, size_t SS,
    size_t in_bstride, size_t out_bstride, int HW)
{
    constexpr int PS = TAPS * CPB * 32 + 8;
    __shared__ ushort smem[32 * PS];
    mg2f_body<CI, TAPS, KCH, CPB>(blockIdx.x, blockIdx.y, blockIdx.z,
        inb, wb, bias, outp, wshift, Wp, NS, SS, in_bstride, out_bstride, HW, smem);
}

// fused inorm-apply (mode2: v+2r) -> NHWC bf16; stats from f64 accumulators
__global__ __launch_bounds__(256) void iapad_k(const float* __restrict__ in,
    const double* __restrict__ sta, ushort* __restrict__ ob, int HW, int Co)
{
    int i4 = (blockIdx.x * 256 + threadIdx.x) * 4;
    int ch = i4 / HW;
    int p = i4 - ch * HW;
    int b = ch / Co, c = ch - b * Co;
    double S = sta[2 * ch], S2 = sta[2 * ch + 1];
    double md = S / (double)HW;
    double vr = S2 / (double)HW - md * md;
    float m = (float)md;
    float inv = rsqrtf((float)(vr < 0.0 ? 0.0 : vr) + EPS);
    float4 v = *(const float4*)(in + i4);
    ushort* op = ob + ((size_t)b * HW + p) * Co + c;
    op[0]              = f2b(v.x + 2.f * (v.x - m) * inv);
    op[(size_t)Co]     = f2b(v.y + 2.f * (v.y - m) * inv);
    op[(size_t)Co * 2] = f2b(v.z + 2.f * (v.z - m) * inv);
    op[(size_t)Co * 3] = f2b(v.w + 2.f * (v.w - m) * inv);
}

// ================= Direct 3x3 conv fp32 (final 32->3) ==========================
// optional sta (f64 Σ/Σ² per chan): applies x' = x + 2*inorm(x) on load
template<int NCO>
__global__ __launch_bounds__(256) void conv3x3_d(const float* __restrict__ in,
    const float* __restrict__ w, const float* __restrict__ bias,
    float* __restrict__ outp, const double* __restrict__ sta,
    int Ci, int CS, int H, int W, int Co, int NS, size_t SS)
{
    int z = blockIdx.z;
    int b = z / NS, sl = z - b * NS;
    int WC = W >> 2;
    int idx = blockIdx.x * 256 + threadIdx.x;
    int xc = idx % WC, y = idx / WC;
    int x0 = xc << 2;
    bool lz = (x0 == 0), rz = (x0 + 4 == W);
    int co0 = blockIdx.y * NCO;
    float acc[NCO][4];
    #pragma unroll
    for (int j = 0; j < NCO; j++)
        #pragma unroll
        for (int p = 0; p < 4; p++) acc[j][p] = 0.f;

    const float* ib = in + ((size_t)b * Ci + sl * CS) * H * W;
    for (int ci = 0; ci < CS; ci++) {
        const float* ic = ib + (size_t)ci * H * W;
        int cig = sl * CS + ci;
        float sa = 1.f, sb = 0.f;
        if (sta) {
            int chg = b * Ci + cig;
            double S = sta[2 * chg], S2 = sta[2 * chg + 1];
            double n = (double)H * W;
            double md = S / n;
            double vr = S2 / n - md * md;
            float inv = rsqrtf((float)(vr < 0.0 ? 0.0 : vr) + EPS);
            sa = 1.f + 2.f * inv;
            sb = -2.f * (float)md * inv;
        }
        float e[3][6];
        #pragma unroll
        for (int r = 0; r < 3; r++) {
            int yy = y + r - 1;
            float4 v = make_float4(0.f, 0.f, 0.f, 0.f);
            if (yy >= 0 && yy < H) {
                v = *(const float4*)(ic + (size_t)yy * W + x0);
                if (sta) {
                    v.x = fmaf(v.x, sa, sb); v.y = fmaf(v.y, sa, sb);
                    v.z = fmaf(v.z, sa, sb); v.w = fmaf(v.w, sa, sb);
                }
            }
            float lf = __shfl_up(v.w, 1);
            float rt = __shfl_down(v.x, 1);
            e[r][0] = lz ? 0.f : lf;
            e[r][1] = v.x; e[r][2] = v.y; e[r][3] = v.z; e[r][4] = v.w;
            e[r][5] = rz ? 0.f : rt;
        }
        #pragma unroll
        for (int j = 0; j < NCO; j++) {
            const float* wj = w + ((size_t)(co0 + j) * Ci + cig) * 9;
            #pragma unroll
            for (int r = 0; r < 3; r++) {
                float w0 = wj[3 * r], w1 = wj[3 * r + 1], w2 = wj[3 * r + 2];
                #pragma unroll
                for (int p = 0; p < 4; p++)
                    acc[j][p] = fmaf(e[r][p], w0,
                                fmaf(e[r][p + 1], w1,
                                fmaf(e[r][p + 2], w2, acc[j][p])));
            }
        }
    }
    size_t HW = (size_t)H * W;
    #pragma unroll
    for (int j = 0; j < NCO; j++) {
        float bb = bias ? bias[co0 + j] : 0.f;
        float4 o = make_float4(acc[j][0] + bb, acc[j][1] + bb,
                               acc[j][2] + bb, acc[j][3] + bb);
        float* op = outp + (size_t)sl * SS
                  + ((size_t)b * Co + co0 + j) * HW + (size_t)y * W + x0;
        *(float4*)op = o;
    }
}

// ================= reduce partials (+bias, optional residual) ==================
__global__ __launch_bounds__(256) void reduce_k(const float* __restrict__ part,
    const float* __restrict__ bias, const float* res, float* out,
    int HW, int Co, int NS, size_t SS)
{
    reduce_body(blockIdx.x, part, bias, res, out, HW, Co, NS, SS);
}

// ================= PacConvT stage B: scatter/gather + fused f64 stats ==========
template<int NCO>
__global__ __launch_bounds__(256) void pacsc_k(const float* __restrict__ Gin,
    const float* __restrict__ K, const float* __restrict__ bias,
    float* __restrict__ out, double* __restrict__ sta,
    int Cout, int Hi, int Wi, size_t gstride)
{
    int b = blockIdx.z;
    int H = Hi << 1, W = Wi << 1;
    int HW = H * W, HWi = Hi * Wi, WC = W >> 2;
    int idx = blockIdx.x * 256 + threadIdx.x;
    int half = (H >> 1) * WC;
    int py = (idx >= half) ? 1 : 0;
    int r = idx - py * half;
    int ry = r / WC;
    int y = 2 * ry + py;
    int x0 = (r - ry * WC) << 2;
    int yi = y >> 1, xi0 = x0 >> 1;
    int co0 = blockIdx.y * NCO;
    const float* G  = Gin + (size_t)b * gstride;
    const float* Kb = K + (size_t)b * 9 * HW;
    float* ob = out + (size_t)b * Cout * HW;
    size_t krow = (size_t)y * W + x0;
    bool vok = (xi0 + 2 < Wi);

    double ts[NCO], ts2[NCO];
    #pragma unroll
    for (int j = 0; j < NCO; j++) { ts[j] = 0.0; ts2[j] = 0.0; }

    if (py == 0) {
        float k4a = Kb[(size_t)4 * HW + krow],     k4b = Kb[(size_t)4 * HW + krow + 2];
        float k3a = Kb[(size_t)3 * HW + krow + 1], k3b = Kb[(size_t)3 * HW + krow + 3];
        float k5a = Kb[(size_t)5 * HW + krow + 1], k5b = Kb[(size_t)5 * HW + krow + 3];
        #pragma unroll
        for (int j = 0; j < NCO; j++) {
            int co = co0 + j;
            size_t rowb = (size_t)yi * Wi + xi0;
            const float* g3 = G + (size_t)(3 * Cout + co) * HWi + rowb;
            const float* g4 = G + (size_t)(4 * Cout + co) * HWi + rowb;
            const float* g5 = G + (size_t)(5 * Cout + co) * HWi + rowb;
            float bb = bias[co];
            float g5b = vok ? g5[2] : 0.f;
            float o0 = fmaf(k4a, g4[0], bb);
            float o1 = fmaf(k3a, g3[0], fmaf(k5a, g5[1], bb));
            float o2 = fmaf(k4b, g4[1], bb);
            float o3 = fmaf(k3b, g3[1], fmaf(k5b, g5b, bb));
            *(float4*)(ob + (size_t)co * HW + krow) = make_float4(o0, o1, o2, o3);
            ts[j]  += (double)o0 + o1 + o2 + o3;
            ts2[j] += (double)o0 * o0 + (double)o1 * o1
                    + (double)o2 * o2 + (double)o3 * o3;
        }
    } else {
        bool yok = (yi + 1 < Hi);
        float k1a = Kb[(size_t)1 * HW + krow],     k1b = Kb[(size_t)1 * HW + krow + 2];
        float k7a = Kb[(size_t)7 * HW + krow],     k7b = Kb[(size_t)7 * HW + krow + 2];
        float k0a = Kb[(size_t)0 * HW + krow + 1], k0b = Kb[(size_t)0 * HW + krow + 3];
        float k2a = Kb[(size_t)2 * HW + krow + 1], k2b = Kb[(size_t)2 * HW + krow + 3];
        float k6a = Kb[(size_t)6 * HW + krow + 1], k6b = Kb[(size_t)6 * HW + krow + 3];
        float k8a = Kb[(size_t)8 * HW + krow + 1], k8b = Kb[(size_t)8 * HW + krow + 3];
        #pragma unroll
        for (int j = 0; j < NCO; j++) {
            int co = co0 + j;
            size_t row0 = (size_t)yi * Wi + xi0;
            size_t row1 = (size_t)(yi + 1) * Wi + xi0;
            const float* g0 = G + (size_t)(0 * Cout + co) * HWi + row0;
            const float* g1 = G + (size_t)(1 * Cout + co) * HWi + row0;
            const float* g2 = G + (size_t)(2 * Cout + co) * HWi + row0;
            const float* g6 = G + (size_t)(6 * Cout + co) * HWi + row1;
            const float* g7 = G + (size_t)(7 * Cout + co) * HWi + row1;
            const float* g8 = G + (size_t)(8 * Cout + co) * HWi + row1;
            float bb = bias[co];
            float g2b = vok ? g2[2] : 0.f;
            float g6a = yok ? g6[0] : 0.f, g6b = yok ? g6[1] : 0.f;
            float g7a = yok ? g7[0] : 0.f, g7b = yok ? g7[1] : 0.f;
            float g8a = yok ? g8[1] : 0.f;
            float g8b = (yok && vok) ? g8[2] : 0.f;
            float o0 = fmaf(k1a, g1[0], fmaf(k7a, g7a, bb));
            float o1 = fmaf(k0a, g0[0], fmaf(k2a, g2[1],
                       fmaf(k6a, g6a, fmaf(k8a, g8a, bb))));
            float o2 = fmaf(k1b, g1[1], fmaf(k7b, g7b, bb));
            float o3 = fmaf(k0b, g0[1], fmaf(k2b, g2b,
                       fmaf(k6b, g6b, fmaf(k8b, g8b, bb))));
            *(float4*)(ob + (size_t)co * HW + krow) = make_float4(o0, o1, o2, o3);
            ts[j]  += (double)o0 + o1 + o2 + o3;
            ts2[j] += (double)o0 * o0 + (double)o1 * o1
                    + (double)o2 * o2 + (double)o3 * o3;
        }
    }

    // block-reduce Σ/Σ² per co, one pair of f64 atomics per co per block
    __shared__ double sred[8];
    int l = threadIdx.x & 63, wv = threadIdx.x >> 6;
    #pragma unroll
    for (int j = 0; j < NCO; j++) {
        double s = ts[j], s2 = ts2[j];
        for (int off = 32; off > 0; off >>= 1) {
            s  += __shfl_down(s, off);
            s2 += __shfl_down(s2, off);
        }
        if (l == 0) { sred[wv] = s; sred[4 + wv] = s2; }
        __syncthreads();
        if (threadIdx.x == 0) {
            double S  = sred[0] + sred[1] + sred[2] + sred[3];
            double S2 = sred[4] + sred[5] + sred[6] + sred[7];
            int co = co0 + j;
            atomicAdd(&sta[(size_t)(b * Cout + co) * 2],     S);
            atomicAdd(&sta[(size_t)(b * Cout + co) * 2 + 1], S2);
        }
        __syncthreads();
    }
}

// ==============================================================================
extern "C" void kernel_launch(void* const* d_in, const int* in_sizes, int n_in,
                              void* d_out, int out_size, void* d_ws, size_t ws_size,
                              hipStream_t stream)
{
    const float* x   = (const float*)d_in[0];   // (2,256,64,64)
    const float* ef2 = (const float*)d_in[1];   // (2,64,128,128)
    const float* ef1 = (const float*)d_in[2];   // (2,32,256,256)
    const float* Wd  = (const float*)d_in[3];
    const float* bd  = (const float*)d_in[4];
    const float* Wm  = (const float*)d_in[5];
    const float* bm  = (const float*)d_in[6];
    const float* Wa2 = (const float*)d_in[7];
    const float* ba2 = (const float*)d_in[8];
    const float* Wa1 = (const float*)d_in[9];
    const float* ba1 = (const float*)d_in[10];
    const float* W16 = (const float*)d_in[11];
    const float* b16 = (const float*)d_in[12];
    const float* W20 = (const float*)d_in[13];
    const float* b20 = (const float*)d_in[14];
    const float* W24 = (const float*)d_in[15];
    const float* b24 = (const float*)d_in[16];
    float* out = (float*)d_out;                 // (2,3,256,256)

    // ---- linear no-alias workspace layout (floats); ~235 MB of 256 MiB ----
    float* P = (float*)d_ws;
    size_t o = 0;
    auto take = [&](size_t n) { float* p = P + o; o += n; return p; };
    ushort* padDb  = (ushort*)take(1115136);   // 2x66x66x256 bf16
    ushort* wbD    = (ushort*)take(147456);
    float*  Pd     = take(8388608);            // conv_down partials NS=8
    float*  x1     = take(1048576);
    ushort* x2b    = (ushort*)take(524288);
    ushort* padA2b = (ushort*)take(1081600);   // 2x130x130x64
    ushort* wbA2b  = (ushort*)take(36864);
    float*  g2     = take(4194304);            // full (2,128,128,128)
    float*  PK2    = take(2359296);            // K2 partials NS=8
    float*  K2     = take(294912);
    float*  Gin1   = take(4718592);
    float*  x3     = take(2097152);
    ushort* x3b    = (ushort*)take(1048576);
    ushort* padA1b = (ushort*)take(2130048);   // 2x258x258x32
    ushort* wbA1b  = (ushort*)take(9216);
    float*  g1     = take(8388608);            // full (2,64,256,256)
    float*  PK1    = take(4718592);            // K1 partials NS=4
    float*  K1     = take(1179648);
    float*  Gin2   = take(9437184);            // 2x288x16384
    float*  x5     = take(4194304);
    float*  Pf     = take(1572864);            // final conv partials NS=4
    ushort* wT1b   = (ushort*)take(36864);
    ushort* wT2b   = (ushort*)take(9216);
    float*  ST     = take(1024);               // f32 stats for x (istat path)
    double* STA    = (double*)take(768);       // 384 f64: [0..255] x3, [256..383] x5
    float* st0 = ST;

    // L0: wprep | istat(x) | pad(ef2) | pad(ef1)           [8660 blocks]
    pro_k<<<dim3(8660), dim3(256), 0, stream>>>(
        x, ef2, ef1, W16, W20, Wd, Wa2, Wa1,
        wT1b, wT2b, wbD, wbA2b, wbA1b, st0, padA2b, padA1b);

    // L1: ipad(x) | adj_lv2 full-K -> g2 | adj_lv1 full-K -> g1  [3714 blocks]
    l1_k<<<dim3(3714), dim3(256), 0, stream>>>(
        x, st0, padDb, padA2b, wbA2b, ba2, g2, padA1b, wbA1b, ba1, g1);

    // L2: packK1 NS=4 | packK2 NS=8 | conv_down NS=8 -> Pd  [1792 blocks]
    l2_k<<<dim3(1792), dim3(256), 0, stream>>>(
        padDb, wbD, Pd, g1, PK1, g2, PK2);

    // L3: zero STA | reduce(Pd)+bias -> x1 | expcomb K1/K2  [2464 blocks]
    l3_k<<<dim3(2464), dim3(256), 0, stream>>>(Pd, bd, x1, PK1, K1, PK2, K2, STA);

    // fused 1x1: full-K + residual + bias -> x2b bf16 NHWC [256 blocks]
    conv1x1f_k<<<dim3(4, 32, 2), dim3(256), 0, stream>>>(x1, Wm, bm, x2b);

    // PacConvT #1: full-K GEMM (N=576, K=128) -> Gin1; scatter+stats -> x3
    mg2f_k<128, 1, 4, 4><<<dim3(16, 18, 2), dim3(256), 0, stream>>>(
        x2b, wT1b, nullptr, Gin1, 0, 0, 1, (size_t)0,
        (size_t)524288, (size_t)2359296, 4096);
    pacsc_k<2><<<dim3(16, 32, 2), dim3(256), 0, stream>>>(
        Gin1, K2, b16, x3, STA, 64, 64, 64, (size_t)2359296);

    // double inorm+res fused into bf16-NHWC stage (stats from pacsc atomics)
    iapad_k<<<dim3(2048), dim3(256), 0, stream>>>(x3, STA, x3b, 16384, 64);

    // PacConvT #2: full-K GEMM (N=288, K=64) -> Gin2; scatter+stats -> x5
    mg2f_k<64, 1, 2, 2><<<dim3(64, 9, 2), dim3(256), 0, stream>>>(
        x3b, wT2b, nullptr, Gin2, 0, 0, 1, (size_t)0,
        (size_t)1048576, (size_t)4718592, 16384);
    pacsc_k<2><<<dim3(64, 16, 2), dim3(256), 0, stream>>>(
        Gin2, K1, b20, x5, STA + 256, 32, 128, 128, (size_t)4718592);

    // final 32->3 @256x256 fp32 with fused x+2*inorm(x): NS=4 -> Pf; reduce -> out
    conv3x3_d<3><<<dim3(64, 1, 8), dim3(256), 0, stream>>>(
        x5, W24, nullptr, Pf, STA + 256, 32, 8, 256, 256, 3, 4, (size_t)393216);
    reduce_k<<<dim3(384), dim3(256), 0, stream>>>(Pf, b24, nullptr, out, 65536, 3, 4, 393216);
}

// Round 11
// 306.511 us; speedup vs baseline: 1.0839x; 1.0839x over previous
//
#include <hip/hip_runtime.h>

#define EPS 1e-5f

typedef short sh8 __attribute__((ext_vector_type(8)));    // 8 x bf16 (4 VGPR)
typedef float f32x4 __attribute__((ext_vector_type(4)));  // MFMA acc frag

__device__ __forceinline__ ushort f2b(float f) {
    unsigned u = __float_as_uint(f);
    u += 0x7fffu + ((u >> 16) & 1u);          // RNE
    return (ushort)(u >> 16);
}

// ====== InstanceNorm stats body: single-pass f64 (deterministic, stable) =======
__device__ __forceinline__ void istat_body(int ch, const float* __restrict__ in,
                                           float* st, int HW)
{
    __shared__ double sh[512];
    const float* p = in + (size_t)ch * HW;
    double s = 0.0, s2 = 0.0;
    for (int i = threadIdx.x * 4; i < HW; i += 1024) {
        float4 v = *(const float4*)(p + i);
        s  += (double)v.x + (double)v.y + (double)v.z + (double)v.w;
        s2 += (double)v.x * v.x + (double)v.y * v.y
            + (double)v.z * v.z + (double)v.w * v.w;
    }
    sh[threadIdx.x] = s; sh[256 + threadIdx.x] = s2;
    __syncthreads();
    for (int o = 128; o > 0; o >>= 1) {
        if ((int)threadIdx.x < o) {
            sh[threadIdx.x]       += sh[threadIdx.x + o];
            sh[256 + threadIdx.x] += sh[256 + threadIdx.x + o];
        }
        __syncthreads();
    }
    if (threadIdx.x == 0) {
        double m = sh[0] / (double)HW;
        double v = sh[256] / (double)HW - m * m;
        st[2 * ch]     = (float)m;
        st[2 * ch + 1] = (float)(v < 0.0 ? 0.0 : v);
    }
}

// ====== fused inorm-apply (mode0) + padded NHWC bf16 stage body ================
__device__ __forceinline__ void ipad_body(int bxi, int b,
    const float* __restrict__ in, const float* __restrict__ st,
    ushort* __restrict__ ob, int C, int H, int W, int pad, int n4)
{
    int idx = bxi * 256 + threadIdx.x;
    if (idx >= n4) return;
    int cpp = C >> 2;
    int pp = idx / cpp, c0 = (idx - pp * cpp) * 4;
    int Wp = W + 2 * pad, Hp = H + 2 * pad;
    int yp = pp / Wp, xp = pp - yp * Wp;
    int y = yp - pad, x = xp - pad;
    ushort4 o;
    if (y >= 0 && y < H && x >= 0 && x < W) {
        size_t HW = (size_t)H * W;
        const float* ib = in + (size_t)b * C * HW + (size_t)y * W + x;
        #pragma unroll
        for (int u = 0; u < 4; u++) {
            int chg = b * C + c0 + u;
            float m = st[2 * chg];
            float inv = rsqrtf(st[2 * chg + 1] + EPS);
            float v = ib[(size_t)(c0 + u) * HW];
            ((ushort*)&o)[u] = f2b((v - m) * inv);
        }
    } else { o.x = o.y = o.z = o.w = 0; }
    *(ushort4*)(ob + ((size_t)b * Hp * Wp + pp) * C + c0) = o;
}

// ====== plain NCHW f32 -> (padded) NHWC bf16 body ==============================
__device__ __forceinline__ void pad_body(int bxi, int b,
    const float* __restrict__ in, ushort* __restrict__ ob,
    int C, int H, int W, int pad, int n4)
{
    int idx = bxi * 256 + threadIdx.x;
    if (idx >= n4) return;
    int cpp = C >> 2;
    int pp = idx / cpp, c0 = (idx - pp * cpp) * 4;
    int Wp = W + 2 * pad, Hp = H + 2 * pad;
    int yp = pp / Wp, xp = pp - yp * Wp;
    int y = yp - pad, x = xp - pad;
    ushort4 o;
    if (y >= 0 && y < H && x >= 0 && x < W) {
        const float* ib = in + ((size_t)b * C) * H * W + (size_t)y * W + x;
        size_t HW = (size_t)H * W;
        o.x = f2b(ib[(size_t)(c0    ) * HW]);
        o.y = f2b(ib[(size_t)(c0 + 1) * HW]);
        o.z = f2b(ib[(size_t)(c0 + 2) * HW]);
        o.w = f2b(ib[(size_t)(c0 + 3) * HW]);
    } else { o.x = o.y = o.z = o.w = 0; }
    *(ushort4*)(ob + ((size_t)b * Hp * Wp + pp) * C + c0) = o;
}

// ====== fused weight prep body (all bf16 layers) ===============================
__device__ __forceinline__ void wprep_body(int bxi,
    const float* W16, const float* W20, const float* Wd, const float* Wa2,
    const float* Wa1,
    ushort* wT1b, ushort* wT2b, ushort* wbD, ushort* wbA2b, ushort* wbA1b)
{
    int idx = bxi * 256 + threadIdx.x;
    if (idx < 73728) {                       // wT1b: convT (128,64) -> [t*64+o][ci]
        int to = idx / 128, ci = idx - to * 128;
        int t = to / 64, o = to - t * 64;
        wT1b[idx] = f2b(W16[((size_t)ci * 64 + o) * 9 + t]);
        return;
    } idx -= 73728;
    if (idx < 18432) {                       // wT2b: convT (64,32)
        int to = idx / 64, ci = idx - to * 64;
        int t = to / 32, o = to - t * 32;
        wT2b[idx] = f2b(W20[((size_t)ci * 32 + o) * 9 + t]);
        return;
    } idx -= 18432;
    if (idx < 294912) {                      // wbD: OIHW(128,256) -> [co][t][ci]
        int co = idx / 2304, r = idx - co * 2304;
        int t = r / 256, ci = r - t * 256;
        wbD[idx] = f2b(Wd[((size_t)co * 256 + ci) * 9 + t]);
        return;
    } idx -= 294912;
    if (idx < 73728) {                       // wbA2b: OIHW(128,64)
        int co = idx / 576, r = idx - co * 576;
        int t = r / 64, ci = r - t * 64;
        wbA2b[idx] = f2b(Wa2[((size_t)co * 64 + ci) * 9 + t]);
        return;
    } idx -= 73728;
    if (idx < 18432) {                       // wbA1b: OIHW(64,32)
        int co = idx / 288, r = idx - co * 288;
        int t = r / 32, ci = r - t * 32;
        wbA1b[idx] = f2b(Wa1[((size_t)co * 32 + ci) * 9 + t]);
        return;
    }
}

// ====== MFMA GEMM (R8 optimum): 32px/wave, chunked B-LDS, A prefetch-2 =========
// block: 128 px x 32 n (4 waves, each 32px x 32n). KCH 32-ch chunks per slice,
// CPB chunks staged per barrier round. LDS = 32 * (TAPS*CPB*32 + 8) ushorts.
// NOTE: prefetch depth 2 + 32px/wave is the measured optimum (VGPR 84, occ 26%);
//       depth-3 (+4 VGPR) and 64px/wave (144 VGPR, occ cliff) both regressed.
template<int CI, int TAPS, int KCH, int CPB>
__device__ __forceinline__ void mg2f_body(int bx, int by, int bz,
    const ushort* __restrict__ inb, const ushort* __restrict__ wb,
    const float* __restrict__ bias, float* __restrict__ outp,
    int wshift, int Wp, int NS, size_t SS,
    size_t in_bstride, size_t out_bstride, int HW, ushort* bsm)
{
    constexpr int CPBSH = (CPB == 1) ? 0 : (CPB == 2) ? 1 : 2;
    constexpr int SPR   = TAPS * CPB;          // steps per round
    constexpr int TOT   = TAPS * KCH;          // k-steps per slice
    constexpr int PS    = SPR * 32 + 8;        // LDS row stride (2-way free)

    int b = bz / NS, sl = bz - b * NS;
    int cilo = sl * (KCH * 32);
    int tid = threadIdx.x;
    int wv = tid >> 6, l = tid & 63;
    int lane16 = l & 15, quad = l >> 4;
    int klane = quad * 8;
    int pb = bx * 128 + wv * 32;
    int nb0 = by * 32;

    int base[2];
    #pragma unroll
    for (int i = 0; i < 2; i++) {
        int pm = pb + i * 16 + lane16;
        if (TAPS == 9) {
            int W = 1 << wshift;
            int y = pm >> wshift, xx = pm & (W - 1);
            base[i] = (y + 1) * Wp + (xx + 1);
        } else base[i] = pm;
    }
    int nn[2];
    nn[0] = nb0 + lane16; nn[1] = nb0 + 16 + lane16;

    const ushort* inbb = inb + (size_t)b * in_bstride + cilo + klane;
    const ushort* wbs  = wb + cilo;
    const ushort* bp0 = bsm + lane16 * PS + klane;
    const ushort* bp1 = bsm + (16 + lane16) * PS + klane;

    f32x4 vz = {0.f, 0.f, 0.f, 0.f};
    f32x4 acc[2][2] = {{vz, vz}, {vz, vz}};
    sh8 A[3][2];

    #define LDA(ss, av) { \
        int r_ = (ss) / SPR; int l_ = (ss) - r_ * SPR; \
        int t_ = l_ >> CPBSH; int ch_ = r_ * CPB + (l_ & (CPB - 1)); \
        int dof_ = 0; \
        if (TAPS == 9) { \
            int dy_ = (t_ * 43) >> 7; \
            int dx_ = t_ - dy_ * 3; \
            dof_ = (dy_ - 1) * Wp + (dx_ - 1); \
        } \
        int coff_ = ch_ << 5; \
        av[0] = *(const sh8*)(inbb + (size_t)(base[0] + dof_) * CI + coff_); \
        av[1] = *(const sh8*)(inbb + (size_t)(base[1] + dof_) * CI + coff_); \
    }

    LDA(0, A[0])
    if (TOT > 1) LDA(1, A[1])

    #pragma unroll
    for (int r = 0; r < KCH / CPB; r++) {
        if (r) __syncthreads();
        // ---- stage B round r: 32 n x SPR kchunks x 32 ch ----
        {
            constexpr int elems = 32 * SPR * 4;
            for (int j = tid; j < elems; j += 256) {
                int n  = j / (SPR * 4);
                int rr = j - n * (SPR * 4);
                int kc = rr >> 2, c8 = rr & 3;
                int t_ = kc >> CPBSH, co = kc & (CPB - 1);
                int ch_ = r * CPB + co;
                sh8 v = *(const sh8*)(wbs
                    + ((size_t)(nb0 + n) * TAPS + t_) * CI + (ch_ << 5) + (c8 << 3));
                *(sh8*)(bsm + n * PS + (kc << 5) + (c8 << 3)) = v;
            }
        }
        __syncthreads();
        #pragma unroll
        for (int li = 0; li < SPR; li++) {
            const int s = r * SPR + li;
            if (s + 2 < TOT) LDA(s + 2, A[(s + 2) % 3])
            sh8 b0 = *(const sh8*)(bp0 + (li << 5));
            sh8 b1 = *(const sh8*)(bp1 + (li << 5));
            acc[0][0] = __builtin_amdgcn_mfma_f32_16x16x32_bf16(A[s % 3][0], b0, acc[0][0], 0, 0, 0);
            acc[0][1] = __builtin_amdgcn_mfma_f32_16x16x32_bf16(A[s % 3][0], b1, acc[0][1], 0, 0, 0);
            acc[1][0] = __builtin_amdgcn_mfma_f32_16x16x32_bf16(A[s % 3][1], b0, acc[1][0], 0, 0, 0);
            acc[1][1] = __builtin_amdgcn_mfma_f32_16x16x32_bf16(A[s % 3][1], b1, acc[1][1], 0, 0, 0);
        }
    }
    #undef LDA

    float* ob = outp + (size_t)sl * SS + (size_t)b * out_bstride;
    #pragma unroll
    for (int j = 0; j < 2; j++) {
        float bb = bias ? bias[nn[j]] : 0.f;
        #pragma unroll
        for (int i = 0; i < 2; i++) {
            int p0 = pb + i * 16 + quad * 4;
            *(float4*)(ob + (size_t)nn[j] * HW + p0) =
                make_float4(acc[i][j][0] + bb, acc[i][j][1] + bb,
                            acc[i][j][2] + bb, acc[i][j][3] + bb);
        }
    }
}

// ====== PAC gaussian, float4-vectorized (NS=1: fused exp; else partial) ========
__device__ __forceinline__ void pack4_body(int bxi, int zy,
    const float* __restrict__ g, float* __restrict__ part,
    int Cg, int CS, int H, int W, int NS, size_t SS)
{
    int b = zy / NS, sl = zy - b * NS;
    int WC = W >> 2;
    int idx = bxi * 256 + threadIdx.x;
    int y = idx / WC, xc = idx - y * WC;
    int x0 = xc << 2;
    bool lz = (x0 == 0), rz = (x0 + 4 == W);
    float acc[9][4];
    #pragma unroll
    for (int t = 0; t < 9; t++)
        #pragma unroll
        for (int p = 0; p < 4; p++) acc[t][p] = 0.f;

    const float* gb = g + ((size_t)b * Cg + sl * CS) * H * W;
    for (int ci = 0; ci < CS; ci++) {
        const float* gc = gb + (size_t)ci * H * W;
        float e[3][6];
        #pragma unroll
        for (int r = 0; r < 3; r++) {
            int yy = y + r - 1;
            float4 v = make_float4(0.f, 0.f, 0.f, 0.f);
            if (yy >= 0 && yy < H)
                v = *(const float4*)(gc + (size_t)yy * W + x0);
            float lf = __shfl_up(v.w, 1);
            float rt = __shfl_down(v.x, 1);
            e[r][0] = lz ? 0.f : lf;
            e[r][1] = v.x; e[r][2] = v.y; e[r][3] = v.z; e[r][4] = v.w;
            e[r][5] = rz ? 0.f : rt;
        }
        #pragma unroll
        for (int i = 0; i < 3; i++)
            #pragma unroll
            for (int j = 0; j < 3; j++)
                #pragma unroll
                for (int p = 0; p < 4; p++) {
                    float d = e[i][p + j] - e[1][p + 1];
                    acc[i * 3 + j][p] = fmaf(d, d, acc[i * 3 + j][p]);
                }
    }
    size_t HW = (size_t)H * W;
    #pragma unroll
    for (int t = 0; t < 9; t++) {
        float4 o;
        if (NS == 1) {
            o = make_float4(expf(-0.5f * acc[t][0]), expf(-0.5f * acc[t][1]),
                            expf(-0.5f * acc[t][2]), expf(-0.5f * acc[t][3]));
        } else {
            o = make_float4(acc[t][0], acc[t][1], acc[t][2], acc[t][3]);
        }
        *(float4*)(part + (size_t)sl * SS + ((size_t)b * 9 + t) * HW
                   + (size_t)y * W + x0) = o;
    }
}

// ====== reduce partials body (+bias) ===========================================
__device__ __forceinline__ void reduce_body(int bxi,
    const float* __restrict__ part, const float* __restrict__ bias,
    const float* res, float* out, int HW, int Co, int NS, size_t SS)
{
    int i4 = (bxi * 256 + threadIdx.x) * 4;
    float4 a = make_float4(0.f, 0.f, 0.f, 0.f);
    for (int s = 0; s < NS; s++) {
        float4 p = *(const float4*)(part + (size_t)s * SS + i4);
        a.x += p.x; a.y += p.y; a.z += p.z; a.w += p.w;
    }
    int c = (i4 / HW) % Co;
    float bb = bias[c];
    if (res) {
        float4 r = *(const float4*)(res + i4);
        a.x += r.x; a.y += r.y; a.z += r.z; a.w += r.w;
    }
    *(float4*)(out + i4) = make_float4(a.x + bb, a.y + bb, a.z + bb, a.w + bb);
}

__device__ __forceinline__ void expcomb_body(int bxi,
    const float* __restrict__ part, float* __restrict__ K, int NS, size_t SS)
{
    int i4 = (bxi * 256 + threadIdx.x) * 4;
    float4 a = make_float4(0.f, 0.f, 0.f, 0.f);
    for (int s = 0; s < NS; s++) {
        float4 p = *(const float4*)(part + (size_t)s * SS + i4);
        a.x += p.x; a.y += p.y; a.z += p.z; a.w += p.w;
    }
    *(float4*)(K + i4) = make_float4(expf(-0.5f * a.x), expf(-0.5f * a.y),
                                     expf(-0.5f * a.z), expf(-0.5f * a.w));
}

// ================= MEGA KERNELS (dependency-depth fusion) ======================
// L0: wprep(1872) | istat x(512) | pad ef2(2114) | pad ef1(4162)  = 8660 blocks
__global__ __launch_bounds__(256) void pro_k(
    const float* x, const float* ef2, const float* ef1,
    const float* W16, const float* W20, const float* Wd, const float* Wa2,
    const float* Wa1,
    ushort* wT1b, ushort* wT2b, ushort* wbD, ushort* wbA2b, ushort* wbA1b,
    float* st0, ushort* padA2b, ushort* padA1b)
{
    int bid = blockIdx.x;
    if (bid < 1872) {
        wprep_body(bid, W16, W20, Wd, Wa2, Wa1, wT1b, wT2b, wbD, wbA2b, wbA1b);
        return;
    } bid -= 1872;
    if (bid < 512) { istat_body(bid, x, st0, 4096); return; } bid -= 512;
    if (bid < 2114) {
        pad_body(bid % 1057, bid / 1057, ef2, padA2b, 64, 128, 128, 1, 270400);
        return;
    } bid -= 2114;
    pad_body(bid % 2081, bid / 2081, ef1, padA1b, 32, 256, 256, 1, 532512);
}

// L1: adj_lv2(1024) | adj_lv1(2048) | ipad x(2178)  = 5250 blocks
// (long GEMM chains FIRST; short BW-bound ipad blocks drain the tail)
__global__ __launch_bounds__(256) void l1_k(
    const float* x, const float* st0, ushort* padDb,
    const ushort* padA2b, const ushort* wbA2b, const float* ba2, float* g2,
    const ushort* padA1b, const ushort* wbA1b, const float* ba1, float* g1)
{
    __shared__ ushort smem[32 * (9 * 32 + 8)];   // 18944 B
    int bid = blockIdx.x;
    if (bid < 1024) {   // adj_lv2 64->128 @128x128: K=576, 2 rounds
        mg2f_body<64, 9, 2, 1>(bid & 127, (bid >> 7) & 3, bid >> 9,
            padA2b, wbA2b, ba2, g2, 7, 130, 1, (size_t)0,
            (size_t)1081600, (size_t)2097152, 16384, smem);
        return;
    } bid -= 1024;
    if (bid < 2048) {   // adj_lv1 32->64 @256x256: K=288, 1 round
        mg2f_body<32, 9, 1, 1>(bid & 511, (bid >> 9) & 1, bid >> 10,
            padA1b, wbA1b, ba1, g1, 8, 258, 1, (size_t)0,
            (size_t)2130048, (size_t)4194304, 65536, smem);
        return;
    } bid -= 2048;
    ipad_body(bid % 1089, bid / 1089, x, st0, padDb, 256, 64, 64, 1, 278784);
}

// L2: packK1 NS=4(512) | packK2 NS=8(256) | conv_down NS=8(2048) = 2816 blocks
// (long-chain pack blocks FIRST so the drain tail is the short GEMM blocks)
__global__ __launch_bounds__(256) void l2_k(
    const ushort* padDb, const ushort* wbD, float* Pd,
    const float* g1, float* PK1, const float* g2, float* PK2)
{
    __shared__ ushort smem[32 * (9 * 32 + 8)];   // 18944 B
    int bid = blockIdx.x;
    if (bid < 512) {    // PAC K1 partials NS=4, CS=16
        pack4_body(bid & 63, bid >> 6, g1, PK1, 64, 16, 256, 256, 4, (size_t)1179648);
        return;
    } bid -= 512;
    if (bid < 256) {    // PAC K2 partials NS=8, CS=16
        pack4_body(bid & 15, bid >> 4, g2, PK2, 128, 16, 128, 128, 8, (size_t)294912);
        return;
    } bid -= 256;
    // conv_down 256->128 @64x64: 32ch slice, totk=9
    mg2f_body<256, 9, 1, 1>(bid & 31, (bid >> 5) & 3, bid >> 7,
        padDb, wbD, nullptr, Pd, 6, 66, 8, (size_t)1048576,
        (size_t)1115136, (size_t)524288, 4096, smem);
}

// L3: zero STA | reduce Pd(1024) | expcomb K1(1152) | expcomb K2(288) = 2464
__global__ __launch_bounds__(256) void l3_k(
    const float* Pd, const float* bd, float* x1,
    const float* PK1, float* K1, const float* PK2, float* K2, double* sta)
{
    int bid = blockIdx.x;
    if (bid == 0) {
        for (int t = threadIdx.x; t < 384; t += 256) sta[t] = 0.0;
    }
    if (bid < 1024) {
        reduce_body(bid, Pd, bd, nullptr, x1, 4096, 128, 8, (size_t)1048576);
        return;
    } bid -= 1024;
    if (bid < 1152) {
        expcomb_body(bid, PK1, K1, 4, (size_t)1179648);
        return;
    } bid -= 1152;
    expcomb_body(bid, PK2, K2, 8, (size_t)294912);
}

// ================= fused 1x1 conv: full-K + bias + residual -> bf16 NHWC =======
// NCO=4, grid (4,32,2) = 256 blocks
__global__ __launch_bounds__(256) void conv1x1f_k(
    const float* __restrict__ x1, const float* __restrict__ Wm,
    const float* __restrict__ bm, ushort* __restrict__ x2b)
{
    __shared__ float wsm[512];                   // 4 co x 128 ci
    int b = blockIdx.z;
    int co0 = blockIdx.y * 4;
    int tid = threadIdx.x;
    for (int j = tid; j < 512; j += 256) {
        int co = j >> 7, ci = j & 127;
        wsm[j] = Wm[(size_t)(co0 + co) * 128 + ci];
    }
    __syncthreads();
    int px0 = (blockIdx.x * 256 + tid) * 4;
    const float* ib = x1 + (size_t)b * 524288 + px0;
    float acc[4][4];
    #pragma unroll
    for (int j = 0; j < 4; j++)
        #pragma unroll
        for (int p = 0; p < 4; p++) acc[j][p] = 0.f;
    for (int ci = 0; ci < 128; ci++) {
        float4 v = *(const float4*)(ib + (size_t)ci * 4096);
        #pragma unroll
        for (int j = 0; j < 4; j++) {
            float wv = wsm[j * 128 + ci];        // wave-uniform broadcast
            acc[j][0] = fmaf(v.x, wv, acc[j][0]);
            acc[j][1] = fmaf(v.y, wv, acc[j][1]);
            acc[j][2] = fmaf(v.z, wv, acc[j][2]);
            acc[j][3] = fmaf(v.w, wv, acc[j][3]);
        }
    }
    float vals[4][4];
    #pragma unroll
    for (int j = 0; j < 4; j++) {
        float4 r = *(const float4*)(ib + (size_t)(co0 + j) * 4096);
        float bb = bm[co0 + j];
        vals[0][j] = acc[j][0] + r.x + bb;
        vals[1][j] = acc[j][1] + r.y + bb;
        vals[2][j] = acc[j][2] + r.z + bb;
        vals[3][j] = acc[j][3] + r.w + bb;
    }
    #pragma unroll
    for (int p = 0; p < 4; p++) {
        ushort4 ov;
        ov.x = f2b(vals[p][0]); ov.y = f2b(vals[p][1]);
        ov.z = f2b(vals[p][2]); ov.w = f2b(vals[p][3]);
        *(ushort4*)(x2b + ((size_t)b * 4096 + px0 + p) * 128 + co0) = ov;
    }
}

// ================= thin wrappers for the serial tail ===========================
template<int CI, int TAPS, int KCH, int CPB>
__global__ __launch_bounds__(256) void mg2f_k(
    const ushort* __restrict__ inb, const ushort* __restrict__ wb,
    const float* __restrict__ bias, float* __restrict__ outp,
    int wshift, int Wp, int NS, size_t SS,
    size_t in_bstride, size_t out_bstride, int HW)
{
    constexpr int PS = TAPS * CPB * 32 + 8;
    __shared__ ushort smem[32 * PS];
    mg2f_body<CI, TAPS, KCH, CPB>(blockIdx.x, blockIdx.y, blockIdx.z,
        inb, wb, bias, outp, wshift, Wp, NS, SS, in_bstride, out_bstride, HW, smem);
}

// fused inorm-apply (mode2: v+2r) -> NHWC bf16; stats from f64 accumulators
__global__ __launch_bounds__(256) void iapad_k(const float* __restrict__ in,
    const double* __restrict__ sta, ushort* __restrict__ ob, int HW, int Co)
{
    int i4 = (blockIdx.x * 256 + threadIdx.x) * 4;
    int ch = i4 / HW;
    int p = i4 - ch * HW;
    int b = ch / Co, c = ch - b * Co;
    double S = sta[2 * ch], S2 = sta[2 * ch + 1];
    double md = S / (double)HW;
    double vr = S2 / (double)HW - md * md;
    float m = (float)md;
    float inv = rsqrtf((float)(vr < 0.0 ? 0.0 : vr) + EPS);
    float4 v = *(const float4*)(in + i4);
    ushort* op = ob + ((size_t)b * HW + p) * Co + c;
    op[0]              = f2b(v.x + 2.f * (v.x - m) * inv);
    op[(size_t)Co]     = f2b(v.y + 2.f * (v.y - m) * inv);
    op[(size_t)Co * 2] = f2b(v.z + 2.f * (v.z - m) * inv);
    op[(size_t)Co * 3] = f2b(v.w + 2.f * (v.w - m) * inv);
}

// ================= Direct 3x3 conv fp32 (final 32->3) ==========================
// optional sta (f64 Σ/Σ² per chan): applies x' = x + 2*inorm(x) on load
template<int NCO>
__global__ __launch_bounds__(256) void conv3x3_d(const float* __restrict__ in,
    const float* __restrict__ w, const float* __restrict__ bias,
    float* __restrict__ outp, const double* __restrict__ sta,
    int Ci, int CS, int H, int W, int Co, int NS, size_t SS)
{
    int z = blockIdx.z;
    int b = z / NS, sl = z - b * NS;
    int WC = W >> 2;
    int idx = blockIdx.x * 256 + threadIdx.x;
    int xc = idx % WC, y = idx / WC;
    int x0 = xc << 2;
    bool lz = (x0 == 0), rz = (x0 + 4 == W);
    int co0 = blockIdx.y * NCO;
    float acc[NCO][4];
    #pragma unroll
    for (int j = 0; j < NCO; j++)
        #pragma unroll
        for (int p = 0; p < 4; p++) acc[j][p] = 0.f;

    const float* ib = in + ((size_t)b * Ci + sl * CS) * H * W;
    for (int ci = 0; ci < CS; ci++) {
        const float* ic = ib + (size_t)ci * H * W;
        int cig = sl * CS + ci;
        float sa = 1.f, sb = 0.f;
        if (sta) {
            int chg = b * Ci + cig;
            double S = sta[2 * chg], S2 = sta[2 * chg + 1];
            double n = (double)H * W;
            double md = S / n;
            double vr = S2 / n - md * md;
            float inv = rsqrtf((float)(vr < 0.0 ? 0.0 : vr) + EPS);
            sa = 1.f + 2.f * inv;
            sb = -2.f * (float)md * inv;
        }
        float e[3][6];
        #pragma unroll
        for (int r = 0; r < 3; r++) {
            int yy = y + r - 1;
            float4 v = make_float4(0.f, 0.f, 0.f, 0.f);
            if (yy >= 0 && yy < H) {
                v = *(const float4*)(ic + (size_t)yy * W + x0);
                if (sta) {
                    v.x = fmaf(v.x, sa, sb); v.y = fmaf(v.y, sa, sb);
                    v.z = fmaf(v.z, sa, sb); v.w = fmaf(v.w, sa, sb);
                }
            }
            float lf = __shfl_up(v.w, 1);
            float rt = __shfl_down(v.x, 1);
            e[r][0] = lz ? 0.f : lf;
            e[r][1] = v.x; e[r][2] = v.y; e[r][3] = v.z; e[r][4] = v.w;
            e[r][5] = rz ? 0.f : rt;
        }
        #pragma unroll
        for (int j = 0; j < NCO; j++) {
            const float* wj = w + ((size_t)(co0 + j) * Ci + cig) * 9;
            #pragma unroll
            for (int r = 0; r < 3; r++) {
                float w0 = wj[3 * r], w1 = wj[3 * r + 1], w2 = wj[3 * r + 2];
                #pragma unroll
                for (int p = 0; p < 4; p++)
                    acc[j][p] = fmaf(e[r][p], w0,
                                fmaf(e[r][p + 1], w1,
                                fmaf(e[r][p + 2], w2, acc[j][p])));
            }
        }
    }
    size_t HW = (size_t)H * W;
    #pragma unroll
    for (int j = 0; j < NCO; j++) {
        float bb = bias ? bias[co0 + j] : 0.f;
        float4 o = make_float4(acc[j][0] + bb, acc[j][1] + bb,
                               acc[j][2] + bb, acc[j][3] + bb);
        float* op = outp + (size_t)sl * SS
                  + ((size_t)b * Co + co0 + j) * HW + (size_t)y * W + x0;
        *(float4*)op = o;
    }
}

// ================= reduce partials (+bias, optional residual) ==================
__global__ __launch_bounds__(256) void reduce_k(const float* __restrict__ part,
    const float* __restrict__ bias, const float* res, float* out,
    int HW, int Co, int NS, size_t SS)
{
    reduce_body(blockIdx.x, part, bias, res, out, HW, Co, NS, SS);
}

// ================= PacConvT stage B: scatter/gather + fused f64 stats ==========
template<int NCO>
__global__ __launch_bounds__(256) void pacsc_k(const float* __restrict__ Gin,
    const float* __restrict__ K, const float* __restrict__ bias,
    float* __restrict__ out, double* __restrict__ sta,
    int Cout, int Hi, int Wi, size_t gstride)
{
    int b = blockIdx.z;
    int H = Hi << 1, W = Wi << 1;
    int HW = H * W, HWi = Hi * Wi, WC = W >> 2;
    int idx = blockIdx.x * 256 + threadIdx.x;
    int half = (H >> 1) * WC;
    int py = (idx >= half) ? 1 : 0;
    int r = idx - py * half;
    int ry = r / WC;
    int y = 2 * ry + py;
    int x0 = (r - ry * WC) << 2;
    int yi = y >> 1, xi0 = x0 >> 1;
    int co0 = blockIdx.y * NCO;
    const float* G  = Gin + (size_t)b * gstride;
    const float* Kb = K + (size_t)b * 9 * HW;
    float* ob = out + (size_t)b * Cout * HW;
    size_t krow = (size_t)y * W + x0;
    bool vok = (xi0 + 2 < Wi);

    double ts[NCO], ts2[NCO];
    #pragma unroll
    for (int j = 0; j < NCO; j++) { ts[j] = 0.0; ts2[j] = 0.0; }

    if (py == 0) {
        float k4a = Kb[(size_t)4 * HW + krow],     k4b = Kb[(size_t)4 * HW + krow + 2];
        float k3a = Kb[(size_t)3 * HW + krow + 1], k3b = Kb[(size_t)3 * HW + krow + 3];
        float k5a = Kb[(size_t)5 * HW + krow + 1], k5b = Kb[(size_t)5 * HW + krow + 3];
        #pragma unroll
        for (int j = 0; j < NCO; j++) {
            int co = co0 + j;
            size_t rowb = (size_t)yi * Wi + xi0;
            const float* g3 = G + (size_t)(3 * Cout + co) * HWi + rowb;
            const float* g4 = G + (size_t)(4 * Cout + co) * HWi + rowb;
            const float* g5 = G + (size_t)(5 * Cout + co) * HWi + rowb;
            float bb = bias[co];
            float g5b = vok ? g5[2] : 0.f;
            float o0 = fmaf(k4a, g4[0], bb);
            float o1 = fmaf(k3a, g3[0], fmaf(k5a, g5[1], bb));
            float o2 = fmaf(k4b, g4[1], bb);
            float o3 = fmaf(k3b, g3[1], fmaf(k5b, g5b, bb));
            *(float4*)(ob + (size_t)co * HW + krow) = make_float4(o0, o1, o2, o3);
            ts[j]  += (double)o0 + o1 + o2 + o3;
            ts2[j] += (double)o0 * o0 + (double)o1 * o1
                    + (double)o2 * o2 + (double)o3 * o3;
        }
    } else {
        bool yok = (yi + 1 < Hi);
        float k1a = Kb[(size_t)1 * HW + krow],     k1b = Kb[(size_t)1 * HW + krow + 2];
        float k7a = Kb[(size_t)7 * HW + krow],     k7b = Kb[(size_t)7 * HW + krow + 2];
        float k0a = Kb[(size_t)0 * HW + krow + 1], k0b = Kb[(size_t)0 * HW + krow + 3];
        float k2a = Kb[(size_t)2 * HW + krow + 1], k2b = Kb[(size_t)2 * HW + krow + 3];
        float k6a = Kb[(size_t)6 * HW + krow + 1], k6b = Kb[(size_t)6 * HW + krow + 3];
        float k8a = Kb[(size_t)8 * HW + krow + 1], k8b = Kb[(size_t)8 * HW + krow + 3];
        #pragma unroll
        for (int j = 0; j < NCO; j++) {
            int co = co0 + j;
            size_t row0 = (size_t)yi * Wi + xi0;
            size_t row1 = (size_t)(yi + 1) * Wi + xi0;
            const float* g0 = G + (size_t)(0 * Cout + co) * HWi + row0;
            const float* g1 = G + (size_t)(1 * Cout + co) * HWi + row0;
            const float* g2 = G + (size_t)(2 * Cout + co) * HWi + row0;
            const float* g6 = G + (size_t)(6 * Cout + co) * HWi + row1;
            const float* g7 = G + (size_t)(7 * Cout + co) * HWi + row1;
            const float* g8 = G + (size_t)(8 * Cout + co) * HWi + row1;
            float bb = bias[co];
            float g2b = vok ? g2[2] : 0.f;
            float g6a = yok ? g6[0] : 0.f, g6b = yok ? g6[1] : 0.f;
            float g7a = yok ? g7[0] : 0.f, g7b = yok ? g7[1] : 0.f;
            float g8a = yok ? g8[1] : 0.f;
            float g8b = (yok && vok) ? g8[2] : 0.f;
            float o0 = fmaf(k1a, g1[0], fmaf(k7a, g7a, bb));
            float o1 = fmaf(k0a, g0[0], fmaf(k2a, g2[1],
                       fmaf(k6a, g6a, fmaf(k8a, g8a, bb))));
            float o2 = fmaf(k1b, g1[1], fmaf(k7b, g7b, bb));
            float o3 = fmaf(k0b, g0[1], fmaf(k2b, g2b,
                       fmaf(k6b, g6b, fmaf(k8b, g8b, bb))));
            *(float4*)(ob + (size_t)co * HW + krow) = make_float4(o0, o1, o2, o3);
            ts[j]  += (double)o0 + o1 + o2 + o3;
            ts2[j] += (double)o0 * o0 + (double)o1 * o1
                    + (double)o2 * o2 + (double)o3 * o3;
        }
    }

    // block-reduce Σ/Σ² per co, one pair of f64 atomics per co per block
    __shared__ double sred[8];
    int l = threadIdx.x & 63, wv = threadIdx.x >> 6;
    #pragma unroll
    for (int j = 0; j < NCO; j++) {
        double s = ts[j], s2 = ts2[j];
        for (int off = 32; off > 0; off >>= 1) {
            s  += __shfl_down(s, off);
            s2 += __shfl_down(s2, off);
        }
        if (l == 0) { sred[wv] = s; sred[4 + wv] = s2; }
        __syncthreads();
        if (threadIdx.x == 0) {
            double S  = sred[0] + sred[1] + sred[2] + sred[3];
            double S2 = sred[4] + sred[5] + sred[6] + sred[7];
            int co = co0 + j;
            atomicAdd(&sta[(size_t)(b * Cout + co) * 2],     S);
            atomicAdd(&sta[(size_t)(b * Cout + co) * 2 + 1], S2);
        }
        __syncthreads();
    }
}

// ==============================================================================
extern "C" void kernel_launch(void* const* d_in, const int* in_sizes, int n_in,
                              void* d_out, int out_size, void* d_ws, size_t ws_size,
                              hipStream_t stream)
{
    const float* x   = (const float*)d_in[0];   // (2,256,64,64)
    const float* ef2 = (const float*)d_in[1];   // (2,64,128,128)
    const float* ef1 = (const float*)d_in[2];   // (2,32,256,256)
    const float* Wd  = (const float*)d_in[3];
    const float* bd  = (const float*)d_in[4];
    const float* Wm  = (const float*)d_in[5];
    const float* bm  = (const float*)d_in[6];
    const float* Wa2 = (const float*)d_in[7];
    const float* ba2 = (const float*)d_in[8];
    const float* Wa1 = (const float*)d_in[9];
    const float* ba1 = (const float*)d_in[10];
    const float* W16 = (const float*)d_in[11];
    const float* b16 = (const float*)d_in[12];
    const float* W20 = (const float*)d_in[13];
    const float* b20 = (const float*)d_in[14];
    const float* W24 = (const float*)d_in[15];
    const float* b24 = (const float*)d_in[16];
    float* out = (float*)d_out;                 // (2,3,256,256)

    // ---- linear no-alias workspace layout (floats); ~235 MB of 256 MiB ----
    float* P = (float*)d_ws;
    size_t o = 0;
    auto take = [&](size_t n) { float* p = P + o; o += n; return p; };
    ushort* padDb  = (ushort*)take(1115136);   // 2x66x66x256 bf16
    ushort* wbD    = (ushort*)take(147456);
    float*  Pd     = take(8388608);            // conv_down partials NS=8
    float*  x1     = take(1048576);
    ushort* x2b    = (ushort*)take(524288);
    ushort* padA2b = (ushort*)take(1081600);   // 2x130x130x64
    ushort* wbA2b  = (ushort*)take(36864);
    float*  g2     = take(4194304);            // full (2,128,128,128)
    float*  PK2    = take(2359296);            // K2 partials NS=8
    float*  K2     = take(294912);
    float*  Gin1   = take(4718592);
    float*  x3     = take(2097152);
    ushort* x3b    = (ushort*)take(1048576);
    ushort* padA1b = (ushort*)take(2130048);   // 2x258x258x32
    ushort* wbA1b  = (ushort*)take(9216);
    float*  g1     = take(8388608);            // full (2,64,256,256)
    float*  PK1    = take(4718592);            // K1 partials NS=4
    float*  K1     = take(1179648);
    float*  Gin2   = take(9437184);            // 2x288x16384
    float*  x5     = take(4194304);
    float*  Pf     = take(1572864);            // final conv partials NS=4
    ushort* wT1b   = (ushort*)take(36864);
    ushort* wT2b   = (ushort*)take(9216);
    float*  ST     = take(1024);               // f32 stats for x (istat path)
    double* STA    = (double*)take(768);       // 384 f64: [0..255] x3, [256..383] x5
    float* st0 = ST;

    // L0: wprep | istat(x) | pad(ef2) | pad(ef1)           [8660 blocks]
    pro_k<<<dim3(8660), dim3(256), 0, stream>>>(
        x, ef2, ef1, W16, W20, Wd, Wa2, Wa1,
        wT1b, wT2b, wbD, wbA2b, wbA1b, st0, padA2b, padA1b);

    // L1: adj_lv2 -> g2 | adj_lv1 -> g1 | ipad(x)          [5250 blocks]
    l1_k<<<dim3(5250), dim3(256), 0, stream>>>(
        x, st0, padDb, padA2b, wbA2b, ba2, g2, padA1b, wbA1b, ba1, g1);

    // L2: packK1 NS=4 | packK2 NS=8 | conv_down NS=8 -> Pd  [2816 blocks]
    l2_k<<<dim3(2816), dim3(256), 0, stream>>>(
        padDb, wbD, Pd, g1, PK1, g2, PK2);

    // L3: zero STA | reduce(Pd)+bias -> x1 | expcomb K1/K2  [2464 blocks]
    l3_k<<<dim3(2464), dim3(256), 0, stream>>>(Pd, bd, x1, PK1, K1, PK2, K2, STA);

    // fused 1x1: full-K + residual + bias -> x2b bf16 NHWC [256 blocks]
    conv1x1f_k<<<dim3(4, 32, 2), dim3(256), 0, stream>>>(x1, Wm, bm, x2b);

    // PacConvT #1: full-K GEMM (N=576, K=128) -> Gin1; scatter+stats -> x3
    mg2f_k<128, 1, 4, 4><<<dim3(32, 18, 2), dim3(256), 0, stream>>>(
        x2b, wT1b, nullptr, Gin1, 0, 0, 1, (size_t)0,
        (size_t)524288, (size_t)2359296, 4096);
    pacsc_k<2><<<dim3(16, 32, 2), dim3(256), 0, stream>>>(
        Gin1, K2, b16, x3, STA, 64, 64, 64, (size_t)2359296);

    // double inorm+res fused into bf16-NHWC stage (stats from pacsc atomics)
    iapad_k<<<dim3(2048), dim3(256), 0, stream>>>(x3, STA, x3b, 16384, 64);

    // PacConvT #2: full-K GEMM (N=288, K=64) -> Gin2; scatter+stats -> x5
    mg2f_k<64, 1, 2, 2><<<dim3(128, 9, 2), dim3(256), 0, stream>>>(
        x3b, wT2b, nullptr, Gin2, 0, 0, 1, (size_t)0,
        (size_t)1048576, (size_t)4718592, 16384);
    pacsc_k<2><<<dim3(64, 16, 2), dim3(256), 0, stream>>>(
        Gin2, K1, b20, x5, STA + 256, 32, 128, 128, (size_t)4718592);

    // final 32->3 @256x256 fp32 with fused x+2*inorm(x): NS=4 -> Pf; reduce -> out
    conv3x3_d<3><<<dim3(64, 1, 8), dim3(256), 0, stream>>>(
        x5, W24, nullptr, Pf, STA + 256, 32, 8, 256, 256, 3, 4, (size_t)393216);
    reduce_k<<<dim3(384), dim3(256), 0, stream>>>(Pf, b24, nullptr, out, 65536, 3, 4, 393216);
}

// Round 12
// 305.634 us; speedup vs baseline: 1.0870x; 1.0029x over previous
//
#include <hip/hip_runtime.h>

#define EPS 1e-5f

typedef short sh8 __attribute__((ext_vector_type(8)));    // 8 x bf16 (4 VGPR)
typedef float f32x4 __attribute__((ext_vector_type(4)));  // MFMA acc frag

__device__ __forceinline__ ushort f2b(float f) {
    unsigned u = __float_as_uint(f);
    u += 0x7fffu + ((u >> 16) & 1u);          // RNE
    return (ushort)(u >> 16);
}
__device__ __forceinline__ float b2f(ushort u) {
    return __uint_as_float((unsigned)u << 16);
}

// ====== InstanceNorm stats body: single-pass f64 (deterministic, stable) =======
__device__ __forceinline__ void istat_body(int ch, const float* __restrict__ in,
                                           float* st, int HW)
{
    __shared__ double sh[512];
    const float* p = in + (size_t)ch * HW;
    double s = 0.0, s2 = 0.0;
    for (int i = threadIdx.x * 4; i < HW; i += 1024) {
        float4 v = *(const float4*)(p + i);
        s  += (double)v.x + (double)v.y + (double)v.z + (double)v.w;
        s2 += (double)v.x * v.x + (double)v.y * v.y
            + (double)v.z * v.z + (double)v.w * v.w;
    }
    sh[threadIdx.x] = s; sh[256 + threadIdx.x] = s2;
    __syncthreads();
    for (int o = 128; o > 0; o >>= 1) {
        if ((int)threadIdx.x < o) {
            sh[threadIdx.x]       += sh[threadIdx.x + o];
            sh[256 + threadIdx.x] += sh[256 + threadIdx.x + o];
        }
        __syncthreads();
    }
    if (threadIdx.x == 0) {
        double m = sh[0] / (double)HW;
        double v = sh[256] / (double)HW - m * m;
        st[2 * ch]     = (float)m;
        st[2 * ch + 1] = (float)(v < 0.0 ? 0.0 : v);
    }
}

// ====== fused inorm-apply (mode0) + padded NHWC bf16 stage body ================
__device__ __forceinline__ void ipad_body(int bxi, int b,
    const float* __restrict__ in, const float* __restrict__ st,
    ushort* __restrict__ ob, int C, int H, int W, int pad, int n4)
{
    int idx = bxi * 256 + threadIdx.x;
    if (idx >= n4) return;
    int cpp = C >> 2;
    int pp = idx / cpp, c0 = (idx - pp * cpp) * 4;
    int Wp = W + 2 * pad, Hp = H + 2 * pad;
    int yp = pp / Wp, xp = pp - yp * Wp;
    int y = yp - pad, x = xp - pad;
    ushort4 o;
    if (y >= 0 && y < H && x >= 0 && x < W) {
        size_t HW = (size_t)H * W;
        const float* ib = in + (size_t)b * C * HW + (size_t)y * W + x;
        #pragma unroll
        for (int u = 0; u < 4; u++) {
            int chg = b * C + c0 + u;
            float m = st[2 * chg];
            float inv = rsqrtf(st[2 * chg + 1] + EPS);
            float v = ib[(size_t)(c0 + u) * HW];
            ((ushort*)&o)[u] = f2b((v - m) * inv);
        }
    } else { o.x = o.y = o.z = o.w = 0; }
    *(ushort4*)(ob + ((size_t)b * Hp * Wp + pp) * C + c0) = o;
}

// ====== plain NCHW f32 -> (padded) NHWC bf16 body ==============================
__device__ __forceinline__ void pad_body(int bxi, int b,
    const float* __restrict__ in, ushort* __restrict__ ob,
    int C, int H, int W, int pad, int n4)
{
    int idx = bxi * 256 + threadIdx.x;
    if (idx >= n4) return;
    int cpp = C >> 2;
    int pp = idx / cpp, c0 = (idx - pp * cpp) * 4;
    int Wp = W + 2 * pad, Hp = H + 2 * pad;
    int yp = pp / Wp, xp = pp - yp * Wp;
    int y = yp - pad, x = xp - pad;
    ushort4 o;
    if (y >= 0 && y < H && x >= 0 && x < W) {
        const float* ib = in + ((size_t)b * C) * H * W + (size_t)y * W + x;
        size_t HW = (size_t)H * W;
        o.x = f2b(ib[(size_t)(c0    ) * HW]);
        o.y = f2b(ib[(size_t)(c0 + 1) * HW]);
        o.z = f2b(ib[(size_t)(c0 + 2) * HW]);
        o.w = f2b(ib[(size_t)(c0 + 3) * HW]);
    } else { o.x = o.y = o.z = o.w = 0; }
    *(ushort4*)(ob + ((size_t)b * Hp * Wp + pp) * C + c0) = o;
}

// ====== fused weight prep body (all bf16 layers) ===============================
__device__ __forceinline__ void wprep_body(int bxi,
    const float* W16, const float* W20, const float* Wd, const float* Wa2,
    const float* Wa1,
    ushort* wT1b, ushort* wT2b, ushort* wbD, ushort* wbA2b, ushort* wbA1b)
{
    int idx = bxi * 256 + threadIdx.x;
    if (idx < 73728) {                       // wT1b: convT (128,64) -> [t*64+o][ci]
        int to = idx / 128, ci = idx - to * 128;
        int t = to / 64, o = to - t * 64;
        wT1b[idx] = f2b(W16[((size_t)ci * 64 + o) * 9 + t]);
        return;
    } idx -= 73728;
    if (idx < 18432) {                       // wT2b: convT (64,32)
        int to = idx / 64, ci = idx - to * 64;
        int t = to / 32, o = to - t * 32;
        wT2b[idx] = f2b(W20[((size_t)ci * 32 + o) * 9 + t]);
        return;
    } idx -= 18432;
    if (idx < 294912) {                      // wbD: OIHW(128,256) -> [co][t][ci]
        int co = idx / 2304, r = idx - co * 2304;
        int t = r / 256, ci = r - t * 256;
        wbD[idx] = f2b(Wd[((size_t)co * 256 + ci) * 9 + t]);
        return;
    } idx -= 294912;
    if (idx < 73728) {                       // wbA2b: OIHW(128,64)
        int co = idx / 576, r = idx - co * 576;
        int t = r / 64, ci = r - t * 64;
        wbA2b[idx] = f2b(Wa2[((size_t)co * 64 + ci) * 9 + t]);
        return;
    } idx -= 73728;
    if (idx < 18432) {                       // wbA1b: OIHW(64,32)
        int co = idx / 288, r = idx - co * 288;
        int t = r / 32, ci = r - t * 32;
        wbA1b[idx] = f2b(Wa1[((size_t)co * 32 + ci) * 9 + t]);
        return;
    }
}

// ====== MFMA GEMM (R8 optimum): 32px/wave, chunked B-LDS, A prefetch-2 =========
// block: 128 px x 32 n (4 waves, each 32px x 32n). KCH 32-ch chunks per slice,
// CPB chunks staged per barrier round. LDS = 32 * (TAPS*CPB*32 + 8) ushorts.
// OUTB=1: write bf16 (element-indexed strides unchanged).
// NOTE: prefetch depth 2 + 32px/wave is the measured optimum (VGPR 84, occ 26%);
//       depth-3 (+4 VGPR) and 64px/wave (144 VGPR, occ cliff) both regressed.
template<int CI, int TAPS, int KCH, int CPB, int OUTB>
__device__ __forceinline__ void mg2f_body(int bx, int by, int bz,
    const ushort* __restrict__ inb, const ushort* __restrict__ wb,
    const float* __restrict__ bias, void* __restrict__ outp,
    int wshift, int Wp, int NS, size_t SS,
    size_t in_bstride, size_t out_bstride, int HW, ushort* bsm)
{
    constexpr int CPBSH = (CPB == 1) ? 0 : (CPB == 2) ? 1 : 2;
    constexpr int SPR   = TAPS * CPB;          // steps per round
    constexpr int TOT   = TAPS * KCH;          // k-steps per slice
    constexpr int PS    = SPR * 32 + 8;        // LDS row stride (2-way free)

    int b = bz / NS, sl = bz - b * NS;
    int cilo = sl * (KCH * 32);
    int tid = threadIdx.x;
    int wv = tid >> 6, l = tid & 63;
    int lane16 = l & 15, quad = l >> 4;
    int klane = quad * 8;
    int pb = bx * 128 + wv * 32;
    int nb0 = by * 32;

    int base[2];
    #pragma unroll
    for (int i = 0; i < 2; i++) {
        int pm = pb + i * 16 + lane16;
        if (TAPS == 9) {
            int W = 1 << wshift;
            int y = pm >> wshift, xx = pm & (W - 1);
            base[i] = (y + 1) * Wp + (xx + 1);
        } else base[i] = pm;
    }
    int nn[2];
    nn[0] = nb0 + lane16; nn[1] = nb0 + 16 + lane16;

    const ushort* inbb = inb + (size_t)b * in_bstride + cilo + klane;
    const ushort* wbs  = wb + cilo;
    const ushort* bp0 = bsm + lane16 * PS + klane;
    const ushort* bp1 = bsm + (16 + lane16) * PS + klane;

    f32x4 vz = {0.f, 0.f, 0.f, 0.f};
    f32x4 acc[2][2] = {{vz, vz}, {vz, vz}};
    sh8 A[3][2];

    #define LDA(ss, av) { \
        int r_ = (ss) / SPR; int l_ = (ss) - r_ * SPR; \
        int t_ = l_ >> CPBSH; int ch_ = r_ * CPB + (l_ & (CPB - 1)); \
        int dof_ = 0; \
        if (TAPS == 9) { \
            int dy_ = (t_ * 43) >> 7; \
            int dx_ = t_ - dy_ * 3; \
            dof_ = (dy_ - 1) * Wp + (dx_ - 1); \
        } \
        int coff_ = ch_ << 5; \
        av[0] = *(const sh8*)(inbb + (size_t)(base[0] + dof_) * CI + coff_); \
        av[1] = *(const sh8*)(inbb + (size_t)(base[1] + dof_) * CI + coff_); \
    }

    LDA(0, A[0])
    if (TOT > 1) LDA(1, A[1])

    #pragma unroll
    for (int r = 0; r < KCH / CPB; r++) {
        if (r) __syncthreads();
        // ---- stage B round r: 32 n x SPR kchunks x 32 ch ----
        {
            constexpr int elems = 32 * SPR * 4;
            for (int j = tid; j < elems; j += 256) {
                int n  = j / (SPR * 4);
                int rr = j - n * (SPR * 4);
                int kc = rr >> 2, c8 = rr & 3;
                int t_ = kc >> CPBSH, co = kc & (CPB - 1);
                int ch_ = r * CPB + co;
                sh8 v = *(const sh8*)(wbs
                    + ((size_t)(nb0 + n) * TAPS + t_) * CI + (ch_ << 5) + (c8 << 3));
                *(sh8*)(bsm + n * PS + (kc << 5) + (c8 << 3)) = v;
            }
        }
        __syncthreads();
        #pragma unroll
        for (int li = 0; li < SPR; li++) {
            const int s = r * SPR + li;
            if (s + 2 < TOT) LDA(s + 2, A[(s + 2) % 3])
            sh8 b0 = *(const sh8*)(bp0 + (li << 5));
            sh8 b1 = *(const sh8*)(bp1 + (li << 5));
            acc[0][0] = __builtin_amdgcn_mfma_f32_16x16x32_bf16(A[s % 3][0], b0, acc[0][0], 0, 0, 0);
            acc[0][1] = __builtin_amdgcn_mfma_f32_16x16x32_bf16(A[s % 3][0], b1, acc[0][1], 0, 0, 0);
            acc[1][0] = __builtin_amdgcn_mfma_f32_16x16x32_bf16(A[s % 3][1], b0, acc[1][0], 0, 0, 0);
            acc[1][1] = __builtin_amdgcn_mfma_f32_16x16x32_bf16(A[s % 3][1], b1, acc[1][1], 0, 0, 0);
        }
    }
    #undef LDA

    #pragma unroll
    for (int j = 0; j < 2; j++) {
        float bb = bias ? bias[nn[j]] : 0.f;
        #pragma unroll
        for (int i = 0; i < 2; i++) {
            int p0 = pb + i * 16 + quad * 4;
            if (OUTB) {
                ushort* ob = (ushort*)outp + (size_t)sl * SS + (size_t)b * out_bstride;
                ushort4 ov;
                ov.x = f2b(acc[i][j][0] + bb); ov.y = f2b(acc[i][j][1] + bb);
                ov.z = f2b(acc[i][j][2] + bb); ov.w = f2b(acc[i][j][3] + bb);
                *(ushort4*)(ob + (size_t)nn[j] * HW + p0) = ov;
            } else {
                float* ob = (float*)outp + (size_t)sl * SS + (size_t)b * out_bstride;
                *(float4*)(ob + (size_t)nn[j] * HW + p0) =
                    make_float4(acc[i][j][0] + bb, acc[i][j][1] + bb,
                                acc[i][j][2] + bb, acc[i][j][3] + bb);
            }
        }
    }
}

// ====== PAC gaussian on bf16 g, float4-vectorized (NS=1: fused exp) ============
__device__ __forceinline__ void pack4_body(int bxi, int zy,
    const ushort* __restrict__ g, float* __restrict__ part,
    int Cg, int CS, int H, int W, int NS, size_t SS)
{
    int b = zy / NS, sl = zy - b * NS;
    int WC = W >> 2;
    int idx = bxi * 256 + threadIdx.x;
    int y = idx / WC, xc = idx - y * WC;
    int x0 = xc << 2;
    bool lz = (x0 == 0), rz = (x0 + 4 == W);
    float acc[9][4];
    #pragma unroll
    for (int t = 0; t < 9; t++)
        #pragma unroll
        for (int p = 0; p < 4; p++) acc[t][p] = 0.f;

    const ushort* gb = g + ((size_t)b * Cg + sl * CS) * H * W;
    for (int ci = 0; ci < CS; ci++) {
        const ushort* gc = gb + (size_t)ci * H * W;
        float e[3][6];
        #pragma unroll
        for (int r = 0; r < 3; r++) {
            int yy = y + r - 1;
            float4 v = make_float4(0.f, 0.f, 0.f, 0.f);
            if (yy >= 0 && yy < H) {
                ushort4 u = *(const ushort4*)(gc + (size_t)yy * W + x0);
                v = make_float4(b2f(u.x), b2f(u.y), b2f(u.z), b2f(u.w));
            }
            float lf = __shfl_up(v.w, 1);
            float rt = __shfl_down(v.x, 1);
            e[r][0] = lz ? 0.f : lf;
            e[r][1] = v.x; e[r][2] = v.y; e[r][3] = v.z; e[r][4] = v.w;
            e[r][5] = rz ? 0.f : rt;
        }
        #pragma unroll
        for (int i = 0; i < 3; i++)
            #pragma unroll
            for (int j = 0; j < 3; j++)
                #pragma unroll
                for (int p = 0; p < 4; p++) {
                    float d = e[i][p + j] - e[1][p + 1];
                    acc[i * 3 + j][p] = fmaf(d, d, acc[i * 3 + j][p]);
                }
    }
    size_t HW = (size_t)H * W;
    #pragma unroll
    for (int t = 0; t < 9; t++) {
        float4 o;
        if (NS == 1) {
            o = make_float4(expf(-0.5f * acc[t][0]), expf(-0.5f * acc[t][1]),
                            expf(-0.5f * acc[t][2]), expf(-0.5f * acc[t][3]));
        } else {
            o = make_float4(acc[t][0], acc[t][1], acc[t][2], acc[t][3]);
        }
        *(float4*)(part + (size_t)sl * SS + ((size_t)b * 9 + t) * HW
                   + (size_t)y * W + x0) = o;
    }
}

// ====== reduce partials body (+bias) ===========================================
__device__ __forceinline__ void reduce_body(int bxi,
    const float* __restrict__ part, const float* __restrict__ bias,
    const float* res, float* out, int HW, int Co, int NS, size_t SS)
{
    int i4 = (bxi * 256 + threadIdx.x) * 4;
    float4 a = make_float4(0.f, 0.f, 0.f, 0.f);
    for (int s = 0; s < NS; s++) {
        float4 p = *(const float4*)(part + (size_t)s * SS + i4);
        a.x += p.x; a.y += p.y; a.z += p.z; a.w += p.w;
    }
    int c = (i4 / HW) % Co;
    float bb = bias[c];
    if (res) {
        float4 r = *(const float4*)(res + i4);
        a.x += r.x; a.y += r.y; a.z += r.z; a.w += r.w;
    }
    *(float4*)(out + i4) = make_float4(a.x + bb, a.y + bb, a.z + bb, a.w + bb);
}

__device__ __forceinline__ void expcomb_body(int bxi,
    const float* __restrict__ part, float* __restrict__ K, int NS, size_t SS)
{
    int i4 = (bxi * 256 + threadIdx.x) * 4;
    float4 a = make_float4(0.f, 0.f, 0.f, 0.f);
    for (int s = 0; s < NS; s++) {
        float4 p = *(const float4*)(part + (size_t)s * SS + i4);
        a.x += p.x; a.y += p.y; a.z += p.z; a.w += p.w;
    }
    *(float4*)(K + i4) = make_float4(expf(-0.5f * a.x), expf(-0.5f * a.y),
                                     expf(-0.5f * a.z), expf(-0.5f * a.w));
}

// ================= MEGA KERNELS (dependency-depth fusion) ======================
// L0: wprep(1872) | istat x(512) | pad ef2(2114) | pad ef1(4162)  = 8660 blocks
__global__ __launch_bounds__(256) void pro_k(
    const float* x, const float* ef2, const float* ef1,
    const float* W16, const float* W20, const float* Wd, const float* Wa2,
    const float* Wa1,
    ushort* wT1b, ushort* wT2b, ushort* wbD, ushort* wbA2b, ushort* wbA1b,
    float* st0, ushort* padA2b, ushort* padA1b)
{
    int bid = blockIdx.x;
    if (bid < 1872) {
        wprep_body(bid, W16, W20, Wd, Wa2, Wa1, wT1b, wT2b, wbD, wbA2b, wbA1b);
        return;
    } bid -= 1872;
    if (bid < 512) { istat_body(bid, x, st0, 4096); return; } bid -= 512;
    if (bid < 2114) {
        pad_body(bid % 1057, bid / 1057, ef2, padA2b, 64, 128, 128, 1, 270400);
        return;
    } bid -= 2114;
    pad_body(bid % 2081, bid / 2081, ef1, padA1b, 32, 256, 256, 1, 532512);
}

// L1: adj_lv2(1024) | adj_lv1(2048) | ipad x(2178)  = 5250 blocks
// (long GEMM chains FIRST; short BW-bound ipad blocks drain the tail)
__global__ __launch_bounds__(256) void l1_k(
    const float* x, const float* st0, ushort* padDb,
    const ushort* padA2b, const ushort* wbA2b, const float* ba2, ushort* g2,
    const ushort* padA1b, const ushort* wbA1b, const float* ba1, ushort* g1)
{
    __shared__ ushort smem[32 * (9 * 32 + 8)];   // 18944 B
    int bid = blockIdx.x;
    if (bid < 1024) {   // adj_lv2 64->128 @128x128: K=576, 2 rounds, bf16 out
        mg2f_body<64, 9, 2, 1, 1>(bid & 127, (bid >> 7) & 3, bid >> 9,
            padA2b, wbA2b, ba2, g2, 7, 130, 1, (size_t)0,
            (size_t)1081600, (size_t)2097152, 16384, smem);
        return;
    } bid -= 1024;
    if (bid < 2048) {   // adj_lv1 32->64 @256x256: K=288, 1 round, bf16 out
        mg2f_body<32, 9, 1, 1, 1>(bid & 511, (bid >> 9) & 1, bid >> 10,
            padA1b, wbA1b, ba1, g1, 8, 258, 1, (size_t)0,
            (size_t)2130048, (size_t)4194304, 65536, smem);
        return;
    } bid -= 2048;
    ipad_body(bid % 1089, bid / 1089, x, st0, padDb, 256, 64, 64, 1, 278784);
}

// L2: packK1 NS=4(512) | packK2 NS=8(256) | conv_down NS=8(2048) = 2816 blocks
// (long-chain pack blocks FIRST so the drain tail is the short GEMM blocks)
__global__ __launch_bounds__(256) void l2_k(
    const ushort* padDb, const ushort* wbD, float* Pd,
    const ushort* g1, float* PK1, const ushort* g2, float* PK2)
{
    __shared__ ushort smem[32 * (9 * 32 + 8)];   // 18944 B
    int bid = blockIdx.x;
    if (bid < 512) {    // PAC K1 partials NS=4, CS=16
        pack4_body(bid & 63, bid >> 6, g1, PK1, 64, 16, 256, 256, 4, (size_t)1179648);
        return;
    } bid -= 512;
    if (bid < 256) {    // PAC K2 partials NS=8, CS=16
        pack4_body(bid & 15, bid >> 4, g2, PK2, 128, 16, 128, 128, 8, (size_t)294912);
        return;
    } bid -= 256;
    // conv_down 256->128 @64x64: 32ch slice, totk=9, f32 partials
    mg2f_body<256, 9, 1, 1, 0>(bid & 31, (bid >> 5) & 3, bid >> 7,
        padDb, wbD, nullptr, Pd, 6, 66, 8, (size_t)1048576,
        (size_t)1115136, (size_t)524288, 4096, smem);
}

// L3: zero STA | reduce Pd(1024) | expcomb K1(1152) | expcomb K2(288) = 2464
__global__ __launch_bounds__(256) void l3_k(
    const float* Pd, const float* bd, float* x1,
    const float* PK1, float* K1, const float* PK2, float* K2, double* sta)
{
    int bid = blockIdx.x;
    if (bid == 0) {
        for (int t = threadIdx.x; t < 384; t += 256) sta[t] = 0.0;
    }
    if (bid < 1024) {
        reduce_body(bid, Pd, bd, nullptr, x1, 4096, 128, 8, (size_t)1048576);
        return;
    } bid -= 1024;
    if (bid < 1152) {
        expcomb_body(bid, PK1, K1, 4, (size_t)1179648);
        return;
    } bid -= 1152;
    expcomb_body(bid, PK2, K2, 8, (size_t)294912);
}

// ================= fused 1x1 conv: full-K + bias + residual -> bf16 NHWC =======
// NCO=4, grid (4,32,2) = 256 blocks
__global__ __launch_bounds__(256) void conv1x1f_k(
    const float* __restrict__ x1, const float* __restrict__ Wm,
    const float* __restrict__ bm, ushort* __restrict__ x2b)
{
    __shared__ float wsm[512];                   // 4 co x 128 ci
    int b = blockIdx.z;
    int co0 = blockIdx.y * 4;
    int tid = threadIdx.x;
    for (int j = tid; j < 512; j += 256) {
        int co = j >> 7, ci = j & 127;
        wsm[j] = Wm[(size_t)(co0 + co) * 128 + ci];
    }
    __syncthreads();
    int px0 = (blockIdx.x * 256 + tid) * 4;
    const float* ib = x1 + (size_t)b * 524288 + px0;
    float acc[4][4];
    #pragma unroll
    for (int j = 0; j < 4; j++)
        #pragma unroll
        for (int p = 0; p < 4; p++) acc[j][p] = 0.f;
    for (int ci = 0; ci < 128; ci++) {
        float4 v = *(const float4*)(ib + (size_t)ci * 4096);
        #pragma unroll
        for (int j = 0; j < 4; j++) {
            float wv = wsm[j * 128 + ci];        // wave-uniform broadcast
            acc[j][0] = fmaf(v.x, wv, acc[j][0]);
            acc[j][1] = fmaf(v.y, wv, acc[j][1]);
            acc[j][2] = fmaf(v.z, wv, acc[j][2]);
            acc[j][3] = fmaf(v.w, wv, acc[j][3]);
        }
    }
    float vals[4][4];
    #pragma unroll
    for (int j = 0; j < 4; j++) {
        float4 r = *(const float4*)(ib + (size_t)(co0 + j) * 4096);
        float bb = bm[co0 + j];
        vals[0][j] = acc[j][0] + r.x + bb;
        vals[1][j] = acc[j][1] + r.y + bb;
        vals[2][j] = acc[j][2] + r.z + bb;
        vals[3][j] = acc[j][3] + r.w + bb;
    }
    #pragma unroll
    for (int p = 0; p < 4; p++) {
        ushort4 ov;
        ov.x = f2b(vals[p][0]); ov.y = f2b(vals[p][1]);
        ov.z = f2b(vals[p][2]); ov.w = f2b(vals[p][3]);
        *(ushort4*)(x2b + ((size_t)b * 4096 + px0 + p) * 128 + co0) = ov;
    }
}

// ================= thin wrappers for the serial tail ===========================
template<int CI, int TAPS, int KCH, int CPB, int OUTB>
__global__ __launch_bounds__(256) void mg2f_k(
    const ushort* __restrict__ inb, const ushort* __restrict__ wb,
    const float* __restrict__ bias, void* __restrict__ outp,
    int wshift, int Wp, int NS, size_t SS,
    size_t in_bstride, size_t out_bstride, int HW)
{
    constexpr int PS = TAPS * CPB * 32 + 8;
    __shared__ ushort smem[32 * PS];
    mg2f_body<CI, TAPS, KCH, CPB, OUTB>(blockIdx.x, blockIdx.y, blockIdx.z,
        inb, wb, bias, outp, wshift, Wp, NS, SS, in_bstride, out_bstride, HW, smem);
}

// fused inorm-apply (mode2: v+2r) -> NHWC bf16; stats from f64 accumulators
__global__ __launch_bounds__(256) void iapad_k(const float* __restrict__ in,
    const double* __restrict__ sta, ushort* __restrict__ ob, int HW, int Co)
{
    int i4 = (blockIdx.x * 256 + threadIdx.x) * 4;
    int ch = i4 / HW;
    int p = i4 - ch * HW;
    int b = ch / Co, c = ch - b * Co;
    double S = sta[2 * ch], S2 = sta[2 * ch + 1];
    double md = S / (double)HW;
    double vr = S2 / (double)HW - md * md;
    float m = (float)md;
    float inv = rsqrtf((float)(vr < 0.0 ? 0.0 : vr) + EPS);
    float4 v = *(const float4*)(in + i4);
    ushort* op = ob + ((size_t)b * HW + p) * Co + c;
    op[0]              = f2b(v.x + 2.f * (v.x - m) * inv);
    op[(size_t)Co]     = f2b(v.y + 2.f * (v.y - m) * inv);
    op[(size_t)Co * 2] = f2b(v.z + 2.f * (v.z - m) * inv);
    op[(size_t)Co * 3] = f2b(v.w + 2.f * (v.w - m) * inv);
}

// ================= Direct 3x3 conv fp32 (final 32->3) ==========================
// optional sta (f64 Σ/Σ² per chan): applies x' = x + 2*inorm(x) on load
template<int NCO>
__global__ __launch_bounds__(256) void conv3x3_d(const float* __restrict__ in,
    const float* __restrict__ w, const float* __restrict__ bias,
    float* __restrict__ outp, const double* __restrict__ sta,
    int Ci, int CS, int H, int W, int Co, int NS, size_t SS)
{
    int z = blockIdx.z;
    int b = z / NS, sl = z - b * NS;
    int WC = W >> 2;
    int idx = blockIdx.x * 256 + threadIdx.x;
    int xc = idx % WC, y = idx / WC;
    int x0 = xc << 2;
    bool lz = (x0 == 0), rz = (x0 + 4 == W);
    int co0 = blockIdx.y * NCO;
    float acc[NCO][4];
    #pragma unroll
    for (int j = 0; j < NCO; j++)
        #pragma unroll
        for (int p = 0; p < 4; p++) acc[j][p] = 0.f;

    const float* ib = in + ((size_t)b * Ci + sl * CS) * H * W;
    for (int ci = 0; ci < CS; ci++) {
        const float* ic = ib + (size_t)ci * H * W;
        int cig = sl * CS + ci;
        float sa = 1.f, sb = 0.f;
        if (sta) {
            int chg = b * Ci + cig;
            double S = sta[2 * chg], S2 = sta[2 * chg + 1];
            double n = (double)H * W;
            double md = S / n;
            double vr = S2 / n - md * md;
            float inv = rsqrtf((float)(vr < 0.0 ? 0.0 : vr) + EPS);
            sa = 1.f + 2.f * inv;
            sb = -2.f * (float)md * inv;
        }
        float e[3][6];
        #pragma unroll
        for (int r = 0; r < 3; r++) {
            int yy = y + r - 1;
            float4 v = make_float4(0.f, 0.f, 0.f, 0.f);
            if (yy >= 0 && yy < H) {
                v = *(const float4*)(ic + (size_t)yy * W + x0);
                if (sta) {
                    v.x = fmaf(v.x, sa, sb); v.y = fmaf(v.y, sa, sb);
                    v.z = fmaf(v.z, sa, sb); v.w = fmaf(v.w, sa, sb);
                }
            }
            float lf = __shfl_up(v.w, 1);
            float rt = __shfl_down(v.x, 1);
            e[r][0] = lz ? 0.f : lf;
            e[r][1] = v.x; e[r][2] = v.y; e[r][3] = v.z; e[r][4] = v.w;
            e[r][5] = rz ? 0.f : rt;
        }
        #pragma unroll
        for (int j = 0; j < NCO; j++) {
            const float* wj = w + ((size_t)(co0 + j) * Ci + cig) * 9;
            #pragma unroll
            for (int r = 0; r < 3; r++) {
                float w0 = wj[3 * r], w1 = wj[3 * r + 1], w2 = wj[3 * r + 2];
                #pragma unroll
                for (int p = 0; p < 4; p++)
                    acc[j][p] = fmaf(e[r][p], w0,
                                fmaf(e[r][p + 1], w1,
                                fmaf(e[r][p + 2], w2, acc[j][p])));
            }
        }
    }
    size_t HW = (size_t)H * W;
    #pragma unroll
    for (int j = 0; j < NCO; j++) {
        float bb = bias ? bias[co0 + j] : 0.f;
        float4 o = make_float4(acc[j][0] + bb, acc[j][1] + bb,
                               acc[j][2] + bb, acc[j][3] + bb);
        float* op = outp + (size_t)sl * SS
                  + ((size_t)b * Co + co0 + j) * HW + (size_t)y * W + x0;
        *(float4*)op = o;
    }
}

// ================= reduce partials (+bias, optional residual) ==================
__global__ __launch_bounds__(256) void reduce_k(const float* __restrict__ part,
    const float* __restrict__ bias, const float* res, float* out,
    int HW, int Co, int NS, size_t SS)
{
    reduce_body(blockIdx.x, part, bias, res, out, HW, Co, NS, SS);
}

// ====== PacConvT stage B: scatter/gather on bf16 Gin + fused f64 stats =========
template<int NCO>
__global__ __launch_bounds__(256) void pacsc_k(const ushort* __restrict__ Gin,
    const float* __restrict__ K, const float* __restrict__ bias,
    float* __restrict__ out, double* __restrict__ sta,
    int Cout, int Hi, int Wi, size_t gstride)
{
    int b = blockIdx.z;
    int H = Hi << 1, W = Wi << 1;
    int HW = H * W, HWi = Hi * Wi, WC = W >> 2;
    int idx = blockIdx.x * 256 + threadIdx.x;
    int half = (H >> 1) * WC;
    int py = (idx >= half) ? 1 : 0;
    int r = idx - py * half;
    int ry = r / WC;
    int y = 2 * ry + py;
    int x0 = (r - ry * WC) << 2;
    int yi = y >> 1, xi0 = x0 >> 1;
    int co0 = blockIdx.y * NCO;
    const ushort* G  = Gin + (size_t)b * gstride;
    const float* Kb = K + (size_t)b * 9 * HW;
    float* ob = out + (size_t)b * Cout * HW;
    size_t krow = (size_t)y * W + x0;
    bool vok = (xi0 + 2 < Wi);

    double ts[NCO], ts2[NCO];
    #pragma unroll
    for (int j = 0; j < NCO; j++) { ts[j] = 0.0; ts2[j] = 0.0; }

    if (py == 0) {
        float k4a = Kb[(size_t)4 * HW + krow],     k4b = Kb[(size_t)4 * HW + krow + 2];
        float k3a = Kb[(size_t)3 * HW + krow + 1], k3b = Kb[(size_t)3 * HW + krow + 3];
        float k5a = Kb[(size_t)5 * HW + krow + 1], k5b = Kb[(size_t)5 * HW + krow + 3];
        #pragma unroll
        for (int j = 0; j < NCO; j++) {
            int co = co0 + j;
            size_t rowb = (size_t)yi * Wi + xi0;
            const ushort* g3 = G + (size_t)(3 * Cout + co) * HWi + rowb;
            const ushort* g4 = G + (size_t)(4 * Cout + co) * HWi + rowb;
            const ushort* g5 = G + (size_t)(5 * Cout + co) * HWi + rowb;
            float bb = bias[co];
            float g5b = vok ? b2f(g5[2]) : 0.f;
            float o0 = fmaf(k4a, b2f(g4[0]), bb);
            float o1 = fmaf(k3a, b2f(g3[0]), fmaf(k5a, b2f(g5[1]), bb));
            float o2 = fmaf(k4b, b2f(g4[1]), bb);
            float o3 = fmaf(k3b, b2f(g3[1]), fmaf(k5b, g5b, bb));
            *(float4*)(ob + (size_t)co * HW + krow) = make_float4(o0, o1, o2, o3);
            ts[j]  += (double)o0 + o1 + o2 + o3;
            ts2[j] += (double)o0 * o0 + (double)o1 * o1
                    + (double)o2 * o2 + (double)o3 * o3;
        }
    } else {
        bool yok = (yi + 1 < Hi);
        float k1a = Kb[(size_t)1 * HW + krow],     k1b = Kb[(size_t)1 * HW + krow + 2];
        float k7a = Kb[(size_t)7 * HW + krow],     k7b = Kb[(size_t)7 * HW + krow + 2];
        float k0a = Kb[(size_t)0 * HW + krow + 1], k0b = Kb[(size_t)0 * HW + krow + 3];
        float k2a = Kb[(size_t)2 * HW + krow + 1], k2b = Kb[(size_t)2 * HW + krow + 3];
        float k6a = Kb[(size_t)6 * HW + krow + 1], k6b = Kb[(size_t)6 * HW + krow + 3];
        float k8a = Kb[(size_t)8 * HW + krow + 1], k8b = Kb[(size_t)8 * HW + krow + 3];
        #pragma unroll
        for (int j = 0; j < NCO; j++) {
            int co = co0 + j;
            size_t row0 = (size_t)yi * Wi + xi0;
            size_t row1 = (size_t)(yi + 1) * Wi + xi0;
            const ushort* g0 = G + (size_t)(0 * Cout + co) * HWi + row0;
            const ushort* g1 = G + (size_t)(1 * Cout + co) * HWi + row0;
            const ushort* g2 = G + (size_t)(2 * Cout + co) * HWi + row0;
            const ushort* g6 = G + (size_t)(6 * Cout + co) * HWi + row1;
            const ushort* g7 = G + (size_t)(7 * Cout + co) * HWi + row1;
            const ushort* g8 = G + (size_t)(8 * Cout + co) * HWi + row1;
            float bb = bias[co];
            float g2b = vok ? b2f(g2[2]) : 0.f;
            float g6a = yok ? b2f(g6[0]) : 0.f, g6b = yok ? b2f(g6[1]) : 0.f;
            float g7a = yok ? b2f(g7[0]) : 0.f, g7b = yok ? b2f(g7[1]) : 0.f;
            float g8a = yok ? b2f(g8[1]) : 0.f;
            float g8b = (yok && vok) ? b2f(g8[2]) : 0.f;
            float o0 = fmaf(k1a, b2f(g1[0]), fmaf(k7a, g7a, bb));
            float o1 = fmaf(k0a, b2f(g0[0]), fmaf(k2a, b2f(g2[1]),
                       fmaf(k6a, g6a, fmaf(k8a, g8a, bb))));
            float o2 = fmaf(k1b, b2f(g1[1]), fmaf(k7b, g7b, bb));
            float o3 = fmaf(k0b, b2f(g0[1]), fmaf(k2b, g2b,
                       fmaf(k6b, g6b, fmaf(k8b, g8b, bb))));
            *(float4*)(ob + (size_t)co * HW + krow) = make_float4(o0, o1, o2, o3);
            ts[j]  += (double)o0 + o1 + o2 + o3;
            ts2[j] += (double)o0 * o0 + (double)o1 * o1
                    + (double)o2 * o2 + (double)o3 * o3;
        }
    }

    // block-reduce Σ/Σ² per co, one pair of f64 atomics per co per block
    __shared__ double sred[8];
    int l = threadIdx.x & 63, wv = threadIdx.x >> 6;
    #pragma unroll
    for (int j = 0; j < NCO; j++) {
        double s = ts[j], s2 = ts2[j];
        for (int off = 32; off > 0; off >>= 1) {
            s  += __shfl_down(s, off);
            s2 += __shfl_down(s2, off);
        }
        if (l == 0) { sred[wv] = s; sred[4 + wv] = s2; }
        __syncthreads();
        if (threadIdx.x == 0) {
            double S  = sred[0] + sred[1] + sred[2] + sred[3];
            double S2 = sred[4] + sred[5] + sred[6] + sred[7];
            int co = co0 + j;
            atomicAdd(&sta[(size_t)(b * Cout + co) * 2],     S);
            atomicAdd(&sta[(size_t)(b * Cout + co) * 2 + 1], S2);
        }
        __syncthreads();
    }
}

// ==============================================================================
extern "C" void kernel_launch(void* const* d_in, const int* in_sizes, int n_in,
                              void* d_out, int out_size, void* d_ws, size_t ws_size,
                              hipStream_t stream)
{
    const float* x   = (const float*)d_in[0];   // (2,256,64,64)
    const float* ef2 = (const float*)d_in[1];   // (2,64,128,128)
    const float* ef1 = (const float*)d_in[2];   // (2,32,256,256)
    const float* Wd  = (const float*)d_in[3];
    const float* bd  = (const float*)d_in[4];
    const float* Wm  = (const float*)d_in[5];
    const float* bm  = (const float*)d_in[6];
    const float* Wa2 = (const float*)d_in[7];
    const float* ba2 = (const float*)d_in[8];
    const float* Wa1 = (const float*)d_in[9];
    const float* ba1 = (const float*)d_in[10];
    const float* W16 = (const float*)d_in[11];
    const float* b16 = (const float*)d_in[12];
    const float* W20 = (const float*)d_in[13];
    const float* b20 = (const float*)d_in[14];
    const float* W24 = (const float*)d_in[15];
    const float* b24 = (const float*)d_in[16];
    float* out = (float*)d_out;                 // (2,3,256,256)

    // ---- linear no-alias workspace layout (floats); ~205 MB of 256 MiB ----
    float* P = (float*)d_ws;
    size_t o = 0;
    auto take = [&](size_t n) { float* p = P + o; o += n; return p; };
    ushort* padDb  = (ushort*)take(1115136);   // 2x66x66x256 bf16
    ushort* wbD    = (ushort*)take(147456);
    float*  Pd     = take(8388608);            // conv_down partials NS=8
    float*  x1     = take(1048576);
    ushort* x2b    = (ushort*)take(524288);
    ushort* padA2b = (ushort*)take(1081600);   // 2x130x130x64
    ushort* wbA2b  = (ushort*)take(36864);
    ushort* g2     = (ushort*)take(2097152);   // bf16 full (2,128,128,128)
    float*  PK2    = take(2359296);            // K2 partials NS=8
    float*  K2     = take(294912);
    ushort* Gin1   = (ushort*)take(2359296);   // bf16 2x576x4096
    float*  x3     = take(2097152);
    ushort* x3b    = (ushort*)take(1048576);
    ushort* padA1b = (ushort*)take(2130048);   // 2x258x258x32
    ushort* wbA1b  = (ushort*)take(9216);
    ushort* g1     = (ushort*)take(4194304);   // bf16 full (2,64,256,256)
    float*  PK1    = take(4718592);            // K1 partials NS=4
    float*  K1     = take(1179648);
    ushort* Gin2   = (ushort*)take(4718592);   // bf16 2x288x16384
    float*  x5     = take(4194304);
    float*  Pf     = take(1572864);            // final conv partials NS=4
    ushort* wT1b   = (ushort*)take(36864);
    ushort* wT2b   = (ushort*)take(9216);
    float*  ST     = take(1024);               // f32 stats for x (istat path)
    double* STA    = (double*)take(768);       // 384 f64: [0..255] x3, [256..383] x5
    float* st0 = ST;

    // L0: wprep | istat(x) | pad(ef2) | pad(ef1)           [8660 blocks]
    pro_k<<<dim3(8660), dim3(256), 0, stream>>>(
        x, ef2, ef1, W16, W20, Wd, Wa2, Wa1,
        wT1b, wT2b, wbD, wbA2b, wbA1b, st0, padA2b, padA1b);

    // L1: adj_lv2 -> g2(bf16) | adj_lv1 -> g1(bf16) | ipad(x)  [5250 blocks]
    l1_k<<<dim3(5250), dim3(256), 0, stream>>>(
        x, st0, padDb, padA2b, wbA2b, ba2, g2, padA1b, wbA1b, ba1, g1);

    // L2: packK1 NS=4 | packK2 NS=8 | conv_down NS=8 -> Pd  [2816 blocks]
    l2_k<<<dim3(2816), dim3(256), 0, stream>>>(
        padDb, wbD, Pd, g1, PK1, g2, PK2);

    // L3: zero STA | reduce(Pd)+bias -> x1 | expcomb K1/K2  [2464 blocks]
    l3_k<<<dim3(2464), dim3(256), 0, stream>>>(Pd, bd, x1, PK1, K1, PK2, K2, STA);

    // fused 1x1: full-K + residual + bias -> x2b bf16 NHWC [256 blocks]
    conv1x1f_k<<<dim3(4, 32, 2), dim3(256), 0, stream>>>(x1, Wm, bm, x2b);

    // PacConvT #1: full-K GEMM (N=576, K=128) -> Gin1(bf16); scatter+stats -> x3
    mg2f_k<128, 1, 4, 4, 1><<<dim3(32, 18, 2), dim3(256), 0, stream>>>(
        x2b, wT1b, nullptr, Gin1, 0, 0, 1, (size_t)0,
        (size_t)524288, (size_t)2359296, 4096);
    pacsc_k<2><<<dim3(16, 32, 2), dim3(256), 0, stream>>>(
        Gin1, K2, b16, x3, STA, 64, 64, 64, (size_t)2359296);

    // double inorm+res fused into bf16-NHWC stage (stats from pacsc atomics)
    iapad_k<<<dim3(2048), dim3(256), 0, stream>>>(x3, STA, x3b, 16384, 64);

    // PacConvT #2: full-K GEMM (N=288, K=64) -> Gin2(bf16); scatter+stats -> x5
    mg2f_k<64, 1, 2, 2, 1><<<dim3(128, 9, 2), dim3(256), 0, stream>>>(
        x3b, wT2b, nullptr, Gin2, 0, 0, 1, (size_t)0,
        (size_t)1048576, (size_t)4718592, 16384);
    pacsc_k<2><<<dim3(64, 16, 2), dim3(256), 0, stream>>>(
        Gin2, K1, b20, x5, STA + 256, 32, 128, 128, (size_t)4718592);

    // final 32->3 @256x256 fp32 with fused x+2*inorm(x): NS=4 -> Pf; reduce -> out
    conv3x3_d<3><<<dim3(64, 1, 8), dim3(256), 0, stream>>>(
        x5, W24, nullptr, Pf, STA + 256, 32, 8, 256, 256, 3, 4, (size_t)393216);
    reduce_k<<<dim3(384), dim3(256), 0, stream>>>(Pf, b24, nullptr, out, 65536, 3, 4, 393216);
}

// Round 13
// 296.839 us; speedup vs baseline: 1.1192x; 1.0296x over previous
//
#include <hip/hip_runtime.h>

#define EPS 1e-5f

typedef short sh8 __attribute__((ext_vector_type(8)));    // 8 x bf16 (4 VGPR)
typedef float f32x4 __attribute__((ext_vector_type(4)));  // MFMA acc frag

__device__ __forceinline__ ushort f2b(float f) {
    unsigned u = __float_as_uint(f);
    u += 0x7fffu + ((u >> 16) & 1u);          // RNE
    return (ushort)(u >> 16);
}
__device__ __forceinline__ float b2f(ushort u) {
    return __uint_as_float((unsigned)u << 16);
}

// ====== InstanceNorm stats body: single-pass f64 (deterministic, stable) =======
__device__ __forceinline__ void istat_body(int ch, const float* __restrict__ in,
                                           float* st, int HW)
{
    __shared__ double sh[512];
    const float* p = in + (size_t)ch * HW;
    double s = 0.0, s2 = 0.0;
    for (int i = threadIdx.x * 4; i < HW; i += 1024) {
        float4 v = *(const float4*)(p + i);
        s  += (double)v.x + (double)v.y + (double)v.z + (double)v.w;
        s2 += (double)v.x * v.x + (double)v.y * v.y
            + (double)v.z * v.z + (double)v.w * v.w;
    }
    sh[threadIdx.x] = s; sh[256 + threadIdx.x] = s2;
    __syncthreads();
    for (int o = 128; o > 0; o >>= 1) {
        if ((int)threadIdx.x < o) {
            sh[threadIdx.x]       += sh[threadIdx.x + o];
            sh[256 + threadIdx.x] += sh[256 + threadIdx.x + o];
        }
        __syncthreads();
    }
    if (threadIdx.x == 0) {
        double m = sh[0] / (double)HW;
        double v = sh[256] / (double)HW - m * m;
        st[2 * ch]     = (float)m;
        st[2 * ch + 1] = (float)(v < 0.0 ? 0.0 : v);
    }
}

// ====== fused inorm-apply (mode0) + padded NHWC bf16 stage body ================
__device__ __forceinline__ void ipad_body(int bxi, int b,
    const float* __restrict__ in, const float* __restrict__ st,
    ushort* __restrict__ ob, int C, int H, int W, int pad, int n4)
{
    int idx = bxi * 256 + threadIdx.x;
    if (idx >= n4) return;
    int cpp = C >> 2;
    int pp = idx / cpp, c0 = (idx - pp * cpp) * 4;
    int Wp = W + 2 * pad, Hp = H + 2 * pad;
    int yp = pp / Wp, xp = pp - yp * Wp;
    int y = yp - pad, x = xp - pad;
    ushort4 o;
    if (y >= 0 && y < H && x >= 0 && x < W) {
        size_t HW = (size_t)H * W;
        const float* ib = in + (size_t)b * C * HW + (size_t)y * W + x;
        #pragma unroll
        for (int u = 0; u < 4; u++) {
            int chg = b * C + c0 + u;
            float m = st[2 * chg];
            float inv = rsqrtf(st[2 * chg + 1] + EPS);
            float v = ib[(size_t)(c0 + u) * HW];
            ((ushort*)&o)[u] = f2b((v - m) * inv);
        }
    } else { o.x = o.y = o.z = o.w = 0; }
    *(ushort4*)(ob + ((size_t)b * Hp * Wp + pp) * C + c0) = o;
}

// ====== plain NCHW f32 -> (padded) NHWC bf16 body ==============================
__device__ __forceinline__ void pad_body(int bxi, int b,
    const float* __restrict__ in, ushort* __restrict__ ob,
    int C, int H, int W, int pad, int n4)
{
    int idx = bxi * 256 + threadIdx.x;
    if (idx >= n4) return;
    int cpp = C >> 2;
    int pp = idx / cpp, c0 = (idx - pp * cpp) * 4;
    int Wp = W + 2 * pad, Hp = H + 2 * pad;
    int yp = pp / Wp, xp = pp - yp * Wp;
    int y = yp - pad, x = xp - pad;
    ushort4 o;
    if (y >= 0 && y < H && x >= 0 && x < W) {
        const float* ib = in + ((size_t)b * C) * H * W + (size_t)y * W + x;
        size_t HW = (size_t)H * W;
        o.x = f2b(ib[(size_t)(c0    ) * HW]);
        o.y = f2b(ib[(size_t)(c0 + 1) * HW]);
        o.z = f2b(ib[(size_t)(c0 + 2) * HW]);
        o.w = f2b(ib[(size_t)(c0 + 3) * HW]);
    } else { o.x = o.y = o.z = o.w = 0; }
    *(ushort4*)(ob + ((size_t)b * Hp * Wp + pp) * C + c0) = o;
}

// ====== fused weight prep body (all bf16 layers) ===============================
__device__ __forceinline__ void wprep_body(int bxi,
    const float* W16, const float* W20, const float* Wd, const float* Wa2,
    const float* Wa1,
    ushort* wT1b, ushort* wT2b, ushort* wbD, ushort* wbA2b, ushort* wbA1b)
{
    int idx = bxi * 256 + threadIdx.x;
    if (idx < 73728) {                       // wT1b: convT (128,64) -> [t*64+o][ci]
        int to = idx / 128, ci = idx - to * 128;
        int t = to / 64, o = to - t * 64;
        wT1b[idx] = f2b(W16[((size_t)ci * 64 + o) * 9 + t]);
        return;
    } idx -= 73728;
    if (idx < 18432) {                       // wT2b: convT (64,32)
        int to = idx / 64, ci = idx - to * 64;
        int t = to / 32, o = to - t * 32;
        wT2b[idx] = f2b(W20[((size_t)ci * 32 + o) * 9 + t]);
        return;
    } idx -= 18432;
    if (idx < 294912) {                      // wbD: OIHW(128,256) -> [co][t][ci]
        int co = idx / 2304, r = idx - co * 2304;
        int t = r / 256, ci = r - t * 256;
        wbD[idx] = f2b(Wd[((size_t)co * 256 + ci) * 9 + t]);
        return;
    } idx -= 294912;
    if (idx < 73728) {                       // wbA2b: OIHW(128,64)
        int co = idx / 576, r = idx - co * 576;
        int t = r / 64, ci = r - t * 64;
        wbA2b[idx] = f2b(Wa2[((size_t)co * 64 + ci) * 9 + t]);
        return;
    } idx -= 73728;
    if (idx < 18432) {                       // wbA1b: OIHW(64,32)
        int co = idx / 288, r = idx - co * 288;
        int t = r / 32, ci = r - t * 32;
        wbA1b[idx] = f2b(Wa1[((size_t)co * 32 + ci) * 9 + t]);
        return;
    }
}

// ====== MFMA 9-tap GEMM v2: A-tile AND B staged in LDS =========================
// block: 128 px x 32 n (4 waves, each 32px x 32n). KCH 32-ch rounds.
// A tile: R padded rows x Wt cols x 32 ch, layout [q][row][col][8] (2-way free).
// Per round: cooperative stage (parallel coalesced loads) -> 9 LDS-fed k-steps.
// Critical path per round = 1 global latency + 9 fast steps (was 9 serial).
template<int CI, int KCH, int WSH, int R, int Wt, int OUTB>
__device__ __forceinline__ void mg2s9_body(int bx, int by, int bz,
    const ushort* __restrict__ inb, const ushort* __restrict__ wb,
    const float* __restrict__ bias, void* __restrict__ outp,
    int NS, size_t SS, size_t in_bstride, size_t out_bstride, ushort* sm)
{
    constexpr int W  = 1 << WSH;
    constexpr int Wp = W + 2;
    constexpr int HW = 1 << (2 * WSH);
    constexpr int ABASE = R * Wt * 32;       // A elems
    constexpr int PS = 9 * 32 + 8;           // B row stride (2-way free)

    int b = bz / NS, sl = bz - b * NS;
    int cilo = sl * (KCH * 32);
    int tid = threadIdx.x;
    int wv = tid >> 6, l = tid & 63;
    int lane16 = l & 15, quad = l >> 4;
    int klane = quad * 8;
    int pb = bx * 128 + wv * 32;
    int nb0 = by * 32;
    int ty0 = (bx * 128) >> WSH;             // first unpadded row of px-tile
    int cx0 = (bx * 128) & (W - 1) & ~127;   // 0 except W=256 -> {0,128}

    int al[2], nn[2];
    #pragma unroll
    for (int i = 0; i < 2; i++) {
        int pm = pb + i * 16 + lane16;
        int y = pm >> WSH, xx = pm & (W - 1);
        al[i] = ((quad * R + (y - ty0)) * Wt + (xx - cx0)) * 8;
    }
    nn[0] = nb0 + lane16; nn[1] = nb0 + 16 + lane16;

    const ushort* asrc0 = inb + (size_t)b * in_bstride + cilo;
    const ushort* wbs   = wb + cilo;
    ushort* smB = sm + ABASE;
    const ushort* bp0 = smB + lane16 * PS + klane;
    const ushort* bp1 = smB + (16 + lane16) * PS + klane;

    f32x4 vz = {0.f, 0.f, 0.f, 0.f};
    f32x4 acc[2][2] = {{vz, vz}, {vz, vz}};

    #pragma unroll
    for (int r = 0; r < KCH; r++) {
        if (r) __syncthreads();
        // ---- stage B round r: 32 n x 9 taps x 32 ch ----
        for (int j = tid; j < 32 * 9 * 4; j += 256) {
            int n = j / 36, rr = j - n * 36;
            int t_ = rr >> 2, c8 = rr & 3;
            sh8 v = *(const sh8*)(wbs
                + ((size_t)(nb0 + n) * 9 + t_) * CI + (r << 5) + (c8 << 3));
            *(sh8*)(smB + n * PS + (t_ << 5) + (c8 << 3)) = v;
        }
        // ---- stage A round r: R rows x Wt cols x 32 ch ----
        for (int j = tid; j < R * Wt * 4; j += 256) {
            int g = j >> 2, q = j & 3;
            int rowl = g / Wt, coll = g - rowl * Wt;
            sh8 v = *(const sh8*)(asrc0
                + ((size_t)(ty0 + rowl) * Wp + cx0 + coll) * CI + (r << 5) + (q << 3));
            *(sh8*)(sm + ((q * R + rowl) * Wt + coll) * 8) = v;
        }
        __syncthreads();
        #pragma unroll
        for (int t = 0; t < 9; t++) {
            const int aoff = ((t / 3) * Wt + (t % 3)) * 8;
            sh8 a0 = *(const sh8*)(sm + al[0] + aoff);
            sh8 a1 = *(const sh8*)(sm + al[1] + aoff);
            sh8 b0 = *(const sh8*)(bp0 + (t << 5));
            sh8 b1 = *(const sh8*)(bp1 + (t << 5));
            acc[0][0] = __builtin_amdgcn_mfma_f32_16x16x32_bf16(a0, b0, acc[0][0], 0, 0, 0);
            acc[0][1] = __builtin_amdgcn_mfma_f32_16x16x32_bf16(a0, b1, acc[0][1], 0, 0, 0);
            acc[1][0] = __builtin_amdgcn_mfma_f32_16x16x32_bf16(a1, b0, acc[1][0], 0, 0, 0);
            acc[1][1] = __builtin_amdgcn_mfma_f32_16x16x32_bf16(a1, b1, acc[1][1], 0, 0, 0);
        }
    }

    #pragma unroll
    for (int j = 0; j < 2; j++) {
        float bb = bias ? bias[nn[j]] : 0.f;
        #pragma unroll
        for (int i = 0; i < 2; i++) {
            int p0 = pb + i * 16 + quad * 4;
            if (OUTB) {
                ushort* ob = (ushort*)outp + (size_t)sl * SS + (size_t)b * out_bstride;
                ushort4 ov;
                ov.x = f2b(acc[i][j][0] + bb); ov.y = f2b(acc[i][j][1] + bb);
                ov.z = f2b(acc[i][j][2] + bb); ov.w = f2b(acc[i][j][3] + bb);
                *(ushort4*)(ob + (size_t)nn[j] * HW + p0) = ov;
            } else {
                float* ob = (float*)outp + (size_t)sl * SS + (size_t)b * out_bstride;
                *(float4*)(ob + (size_t)nn[j] * HW + p0) =
                    make_float4(acc[i][j][0] + bb, acc[i][j][1] + bb,
                                acc[i][j][2] + bb, acc[i][j][3] + bb);
            }
        }
    }
}

// ====== MFMA 1-tap GEMM (R8 optimum, PacConvT): B-LDS, A prefetch-2 ============
template<int CI, int TAPS, int KCH, int CPB, int OUTB>
__device__ __forceinline__ void mg2f_body(int bx, int by, int bz,
    const ushort* __restrict__ inb, const ushort* __restrict__ wb,
    const float* __restrict__ bias, void* __restrict__ outp,
    int wshift, int Wp, int NS, size_t SS,
    size_t in_bstride, size_t out_bstride, int HW, ushort* bsm)
{
    constexpr int CPBSH = (CPB == 1) ? 0 : (CPB == 2) ? 1 : 2;
    constexpr int SPR   = TAPS * CPB;          // steps per round
    constexpr int TOT   = TAPS * KCH;          // k-steps per slice
    constexpr int PS    = SPR * 32 + 8;        // LDS row stride (2-way free)

    int b = bz / NS, sl = bz - b * NS;
    int cilo = sl * (KCH * 32);
    int tid = threadIdx.x;
    int wv = tid >> 6, l = tid & 63;
    int lane16 = l & 15, quad = l >> 4;
    int klane = quad * 8;
    int pb = bx * 128 + wv * 32;
    int nb0 = by * 32;

    int base[2];
    #pragma unroll
    for (int i = 0; i < 2; i++) {
        int pm = pb + i * 16 + lane16;
        if (TAPS == 9) {
            int W = 1 << wshift;
            int y = pm >> wshift, xx = pm & (W - 1);
            base[i] = (y + 1) * Wp + (xx + 1);
        } else base[i] = pm;
    }
    int nn[2];
    nn[0] = nb0 + lane16; nn[1] = nb0 + 16 + lane16;

    const ushort* inbb = inb + (size_t)b * in_bstride + cilo + klane;
    const ushort* wbs  = wb + cilo;
    const ushort* bp0 = bsm + lane16 * PS + klane;
    const ushort* bp1 = bsm + (16 + lane16) * PS + klane;

    f32x4 vz = {0.f, 0.f, 0.f, 0.f};
    f32x4 acc[2][2] = {{vz, vz}, {vz, vz}};
    sh8 A[3][2];

    #define LDA(ss, av) { \
        int r_ = (ss) / SPR; int l_ = (ss) - r_ * SPR; \
        int t_ = l_ >> CPBSH; int ch_ = r_ * CPB + (l_ & (CPB - 1)); \
        int dof_ = 0; \
        if (TAPS == 9) { \
            int dy_ = (t_ * 43) >> 7; \
            int dx_ = t_ - dy_ * 3; \
            dof_ = (dy_ - 1) * Wp + (dx_ - 1); \
        } \
        int coff_ = ch_ << 5; \
        av[0] = *(const sh8*)(inbb + (size_t)(base[0] + dof_) * CI + coff_); \
        av[1] = *(const sh8*)(inbb + (size_t)(base[1] + dof_) * CI + coff_); \
    }

    LDA(0, A[0])
    if (TOT > 1) LDA(1, A[1])

    #pragma unroll
    for (int r = 0; r < KCH / CPB; r++) {
        if (r) __syncthreads();
        // ---- stage B round r: 32 n x SPR kchunks x 32 ch ----
        {
            constexpr int elems = 32 * SPR * 4;
            for (int j = tid; j < elems; j += 256) {
                int n  = j / (SPR * 4);
                int rr = j - n * (SPR * 4);
                int kc = rr >> 2, c8 = rr & 3;
                int t_ = kc >> CPBSH, co = kc & (CPB - 1);
                int ch_ = r * CPB + co;
                sh8 v = *(const sh8*)(wbs
                    + ((size_t)(nb0 + n) * TAPS + t_) * CI + (ch_ << 5) + (c8 << 3));
                *(sh8*)(bsm + n * PS + (kc << 5) + (c8 << 3)) = v;
            }
        }
        __syncthreads();
        #pragma unroll
        for (int li = 0; li < SPR; li++) {
            const int s = r * SPR + li;
            if (s + 2 < TOT) LDA(s + 2, A[(s + 2) % 3])
            sh8 b0 = *(const sh8*)(bp0 + (li << 5));
            sh8 b1 = *(const sh8*)(bp1 + (li << 5));
            acc[0][0] = __builtin_amdgcn_mfma_f32_16x16x32_bf16(A[s % 3][0], b0, acc[0][0], 0, 0, 0);
            acc[0][1] = __builtin_amdgcn_mfma_f32_16x16x32_bf16(A[s % 3][0], b1, acc[0][1], 0, 0, 0);
            acc[1][0] = __builtin_amdgcn_mfma_f32_16x16x32_bf16(A[s % 3][1], b0, acc[1][0], 0, 0, 0);
            acc[1][1] = __builtin_amdgcn_mfma_f32_16x16x32_bf16(A[s % 3][1], b1, acc[1][1], 0, 0, 0);
        }
    }
    #undef LDA

    #pragma unroll
    for (int j = 0; j < 2; j++) {
        float bb = bias ? bias[nn[j]] : 0.f;
        #pragma unroll
        for (int i = 0; i < 2; i++) {
            int p0 = pb + i * 16 + quad * 4;
            if (OUTB) {
                ushort* ob = (ushort*)outp + (size_t)sl * SS + (size_t)b * out_bstride;
                ushort4 ov;
                ov.x = f2b(acc[i][j][0] + bb); ov.y = f2b(acc[i][j][1] + bb);
                ov.z = f2b(acc[i][j][2] + bb); ov.w = f2b(acc[i][j][3] + bb);
                *(ushort4*)(ob + (size_t)nn[j] * HW + p0) = ov;
            } else {
                float* ob = (float*)outp + (size_t)sl * SS + (size_t)b * out_bstride;
                *(float4*)(ob + (size_t)nn[j] * HW + p0) =
                    make_float4(acc[i][j][0] + bb, acc[i][j][1] + bb,
                                acc[i][j][2] + bb, acc[i][j][3] + bb);
            }
        }
    }
}

// ====== PAC gaussian on bf16 g, float4-vectorized (NS=1: fused exp) ============
__device__ __forceinline__ void pack4_body(int bxi, int zy,
    const ushort* __restrict__ g, float* __restrict__ part,
    int Cg, int CS, int H, int W, int NS, size_t SS)
{
    int b = zy / NS, sl = zy - b * NS;
    int WC = W >> 2;
    int idx = bxi * 256 + threadIdx.x;
    int y = idx / WC, xc = idx - y * WC;
    int x0 = xc << 2;
    bool lz = (x0 == 0), rz = (x0 + 4 == W);
    float acc[9][4];
    #pragma unroll
    for (int t = 0; t < 9; t++)
        #pragma unroll
        for (int p = 0; p < 4; p++) acc[t][p] = 0.f;

    const ushort* gb = g + ((size_t)b * Cg + sl * CS) * H * W;
    for (int ci = 0; ci < CS; ci++) {
        const ushort* gc = gb + (size_t)ci * H * W;
        float e[3][6];
        #pragma unroll
        for (int r = 0; r < 3; r++) {
            int yy = y + r - 1;
            float4 v = make_float4(0.f, 0.f, 0.f, 0.f);
            if (yy >= 0 && yy < H) {
                ushort4 u = *(const ushort4*)(gc + (size_t)yy * W + x0);
                v = make_float4(b2f(u.x), b2f(u.y), b2f(u.z), b2f(u.w));
            }
            float lf = __shfl_up(v.w, 1);
            float rt = __shfl_down(v.x, 1);
            e[r][0] = lz ? 0.f : lf;
            e[r][1] = v.x; e[r][2] = v.y; e[r][3] = v.z; e[r][4] = v.w;
            e[r][5] = rz ? 0.f : rt;
        }
        #pragma unroll
        for (int i = 0; i < 3; i++)
            #pragma unroll
            for (int j = 0; j < 3; j++)
                #pragma unroll
                for (int p = 0; p < 4; p++) {
                    float d = e[i][p + j] - e[1][p + 1];
                    acc[i * 3 + j][p] = fmaf(d, d, acc[i * 3 + j][p]);
                }
    }
    size_t HW = (size_t)H * W;
    #pragma unroll
    for (int t = 0; t < 9; t++) {
        float4 o;
        if (NS == 1) {
            o = make_float4(expf(-0.5f * acc[t][0]), expf(-0.5f * acc[t][1]),
                            expf(-0.5f * acc[t][2]), expf(-0.5f * acc[t][3]));
        } else {
            o = make_float4(acc[t][0], acc[t][1], acc[t][2], acc[t][3]);
        }
        *(float4*)(part + (size_t)sl * SS + ((size_t)b * 9 + t) * HW
                   + (size_t)y * W + x0) = o;
    }
}

// ====== reduce partials body (+bias) ===========================================
__device__ __forceinline__ void reduce_body(int bxi,
    const float* __restrict__ part, const float* __restrict__ bias,
    const float* res, float* out, int HW, int Co, int NS, size_t SS)
{
    int i4 = (bxi * 256 + threadIdx.x) * 4;
    float4 a = make_float4(0.f, 0.f, 0.f, 0.f);
    for (int s = 0; s < NS; s++) {
        float4 p = *(const float4*)(part + (size_t)s * SS + i4);
        a.x += p.x; a.y += p.y; a.z += p.z; a.w += p.w;
    }
    int c = (i4 / HW) % Co;
    float bb = bias[c];
    if (res) {
        float4 r = *(const float4*)(res + i4);
        a.x += r.x; a.y += r.y; a.z += r.z; a.w += r.w;
    }
    *(float4*)(out + i4) = make_float4(a.x + bb, a.y + bb, a.z + bb, a.w + bb);
}

__device__ __forceinline__ void expcomb_body(int bxi,
    const float* __restrict__ part, float* __restrict__ K, int NS, size_t SS)
{
    int i4 = (bxi * 256 + threadIdx.x) * 4;
    float4 a = make_float4(0.f, 0.f, 0.f, 0.f);
    for (int s = 0; s < NS; s++) {
        float4 p = *(const float4*)(part + (size_t)s * SS + i4);
        a.x += p.x; a.y += p.y; a.z += p.z; a.w += p.w;
    }
    *(float4*)(K + i4) = make_float4(expf(-0.5f * a.x), expf(-0.5f * a.y),
                                     expf(-0.5f * a.z), expf(-0.5f * a.w));
}

// ================= MEGA KERNELS (dependency-depth fusion) ======================
// L0: wprep(1872) | istat x(512) | pad ef2(2114) | pad ef1(4162)  = 8660 blocks
__global__ __launch_bounds__(256) void pro_k(
    const float* x, const float* ef2, const float* ef1,
    const float* W16, const float* W20, const float* Wd, const float* Wa2,
    const float* Wa1,
    ushort* wT1b, ushort* wT2b, ushort* wbD, ushort* wbA2b, ushort* wbA1b,
    float* st0, ushort* padA2b, ushort* padA1b)
{
    int bid = blockIdx.x;
    if (bid < 1872) {
        wprep_body(bid, W16, W20, Wd, Wa2, Wa1, wT1b, wT2b, wbD, wbA2b, wbA1b);
        return;
    } bid -= 1872;
    if (bid < 512) { istat_body(bid, x, st0, 4096); return; } bid -= 512;
    if (bid < 2114) {
        pad_body(bid % 1057, bid / 1057, ef2, padA2b, 64, 128, 128, 1, 270400);
        return;
    } bid -= 2114;
    pad_body(bid % 2081, bid / 2081, ef1, padA1b, 32, 256, 256, 1, 532512);
}

// L1: adj_lv2 A-LDS(1024) | adj_lv1 A-LDS(2048) | ipad x(2178)  = 5250 blocks
// LDS 43904 B (A 24960 + B 18944) -> 3 blocks/CU
__global__ __launch_bounds__(256) void l1_k(
    const float* x, const float* st0, ushort* padDb,
    const ushort* padA2b, const ushort* wbA2b, const float* ba2, ushort* g2,
    const ushort* padA1b, const ushort* wbA1b, const float* ba1, ushort* g1)
{
    __shared__ ushort smem[21952];               // 43904 B
    int bid = blockIdx.x;
    if (bid < 1024) {   // adj_lv2 64->128 @128x128: K=576, 2 rounds, bf16 out
        mg2s9_body<64, 2, 7, 3, 130, 1>(bid & 127, (bid >> 7) & 3, bid >> 9,
            padA2b, wbA2b, ba2, g2, 1, (size_t)0,
            (size_t)1081600, (size_t)2097152, smem);
        return;
    } bid -= 1024;
    if (bid < 2048) {   // adj_lv1 32->64 @256x256: K=288, 1 round, bf16 out
        mg2s9_body<32, 1, 8, 3, 130, 1>(bid & 511, (bid >> 9) & 1, bid >> 10,
            padA1b, wbA1b, ba1, g1, 1, (size_t)0,
            (size_t)2130048, (size_t)4194304, smem);
        return;
    } bid -= 2048;
    ipad_body(bid % 1089, bid / 1089, x, st0, padDb, 256, 64, 64, 1, 278784);
}

// L2: packK1 NS=4(512) | packK2 NS=8(256) | conv_down A-LDS NS=8(2048) = 2816
// LDS 35840 B (A 16896 + B 18944) -> 4 blocks/CU
__global__ __launch_bounds__(256) void l2_k(
    const ushort* padDb, const ushort* wbD, float* Pd,
    const ushort* g1, float* PK1, const ushort* g2, float* PK2)
{
    __shared__ ushort smem[17920];               // 35840 B
    int bid = blockIdx.x;
    if (bid < 512) {    // PAC K1 partials NS=4, CS=16
        pack4_body(bid & 63, bid >> 6, g1, PK1, 64, 16, 256, 256, 4, (size_t)1179648);
        return;
    } bid -= 512;
    if (bid < 256) {    // PAC K2 partials NS=8, CS=16
        pack4_body(bid & 15, bid >> 4, g2, PK2, 128, 16, 128, 128, 8, (size_t)294912);
        return;
    } bid -= 256;
    // conv_down 256->128 @64x64: 32ch slice, 1 round, f32 partials
    mg2s9_body<256, 1, 6, 4, 66, 0>(bid & 31, (bid >> 5) & 3, bid >> 7,
        padDb, wbD, nullptr, Pd, 8, (size_t)1048576,
        (size_t)1115136, (size_t)524288, smem);
}

// L3: zero STA | reduce Pd(1024) | expcomb K1(1152) | expcomb K2(288) = 2464
__global__ __launch_bounds__(256) void l3_k(
    const float* Pd, const float* bd, float* x1,
    const float* PK1, float* K1, const float* PK2, float* K2, double* sta)
{
    int bid = blockIdx.x;
    if (bid == 0) {
        for (int t = threadIdx.x; t < 384; t += 256) sta[t] = 0.0;
    }
    if (bid < 1024) {
        reduce_body(bid, Pd, bd, nullptr, x1, 4096, 128, 8, (size_t)1048576);
        return;
    } bid -= 1024;
    if (bid < 1152) {
        expcomb_body(bid, PK1, K1, 4, (size_t)1179648);
        return;
    } bid -= 1152;
    expcomb_body(bid, PK2, K2, 8, (size_t)294912);
}

// ================= fused 1x1 conv: full-K + bias + residual -> bf16 NHWC =======
// NCO=4, grid (4,32,2) = 256 blocks
__global__ __launch_bounds__(256) void conv1x1f_k(
    const float* __restrict__ x1, const float* __restrict__ Wm,
    const float* __restrict__ bm, ushort* __restrict__ x2b)
{
    __shared__ float wsm[512];                   // 4 co x 128 ci
    int b = blockIdx.z;
    int co0 = blockIdx.y * 4;
    int tid = threadIdx.x;
    for (int j = tid; j < 512; j += 256) {
        int co = j >> 7, ci = j & 127;
        wsm[j] = Wm[(size_t)(co0 + co) * 128 + ci];
    }
    __syncthreads();
    int px0 = (blockIdx.x * 256 + tid) * 4;
    const float* ib = x1 + (size_t)b * 524288 + px0;
    float acc[4][4];
    #pragma unroll
    for (int j = 0; j < 4; j++)
        #pragma unroll
        for (int p = 0; p < 4; p++) acc[j][p] = 0.f;
    for (int ci = 0; ci < 128; ci++) {
        float4 v = *(const float4*)(ib + (size_t)ci * 4096);
        #pragma unroll
        for (int j = 0; j < 4; j++) {
            float wv = wsm[j * 128 + ci];        // wave-uniform broadcast
            acc[j][0] = fmaf(v.x, wv, acc[j][0]);
            acc[j][1] = fmaf(v.y, wv, acc[j][1]);
            acc[j][2] = fmaf(v.z, wv, acc[j][2]);
            acc[j][3] = fmaf(v.w, wv, acc[j][3]);
        }
    }
    float vals[4][4];
    #pragma unroll
    for (int j = 0; j < 4; j++) {
        float4 r = *(const float4*)(ib + (size_t)(co0 + j) * 4096);
        float bb = bm[co0 + j];
        vals[0][j] = acc[j][0] + r.x + bb;
        vals[1][j] = acc[j][1] + r.y + bb;
        vals[2][j] = acc[j][2] + r.z + bb;
        vals[3][j] = acc[j][3] + r.w + bb;
    }
    #pragma unroll
    for (int p = 0; p < 4; p++) {
        ushort4 ov;
        ov.x = f2b(vals[p][0]); ov.y = f2b(vals[p][1]);
        ov.z = f2b(vals[p][2]); ov.w = f2b(vals[p][3]);
        *(ushort4*)(x2b + ((size_t)b * 4096 + px0 + p) * 128 + co0) = ov;
    }
}

// ================= thin wrappers for the serial tail ===========================
template<int CI, int TAPS, int KCH, int CPB, int OUTB>
__global__ __launch_bounds__(256) void mg2f_k(
    const ushort* __restrict__ inb, const ushort* __restrict__ wb,
    const float* __restrict__ bias, void* __restrict__ outp,
    int wshift, int Wp, int NS, size_t SS,
    size_t in_bstride, size_t out_bstride, int HW)
{
    constexpr int PS = TAPS * CPB * 32 + 8;
    __shared__ ushort smem[32 * PS];
    mg2f_body<CI, TAPS, KCH, CPB, OUTB>(blockIdx.x, blockIdx.y, blockIdx.z,
        inb, wb, bias, outp, wshift, Wp, NS, SS, in_bstride, out_bstride, HW, smem);
}

// fused inorm-apply (mode2: v+2r) -> NHWC bf16; stats from f64 accumulators
__global__ __launch_bounds__(256) void iapad_k(const float* __restrict__ in,
    const double* __restrict__ sta, ushort* __restrict__ ob, int HW, int Co)
{
    int i4 = (blockIdx.x * 256 + threadIdx.x) * 4;
    int ch = i4 / HW;
    int p = i4 - ch * HW;
    int b = ch / Co, c = ch - b * Co;
    double S = sta[2 * ch], S2 = sta[2 * ch + 1];
    double md = S / (double)HW;
    double vr = S2 / (double)HW - md * md;
    float m = (float)md;
    float inv = rsqrtf((float)(vr < 0.0 ? 0.0 : vr) + EPS);
    float4 v = *(const float4*)(in + i4);
    ushort* op = ob + ((size_t)b * HW + p) * Co + c;
    op[0]              = f2b(v.x + 2.f * (v.x - m) * inv);
    op[(size_t)Co]     = f2b(v.y + 2.f * (v.y - m) * inv);
    op[(size_t)Co * 2] = f2b(v.z + 2.f * (v.z - m) * inv);
    op[(size_t)Co * 3] = f2b(v.w + 2.f * (v.w - m) * inv);
}

// ================= Direct 3x3 conv fp32 (final 32->3) ==========================
// optional sta (f64 Σ/Σ² per chan): applies x' = x + 2*inorm(x) on load
template<int NCO>
__global__ __launch_bounds__(256) void conv3x3_d(const float* __restrict__ in,
    const float* __restrict__ w, const float* __restrict__ bias,
    float* __restrict__ outp, const double* __restrict__ sta,
    int Ci, int CS, int H, int W, int Co, int NS, size_t SS)
{
    int z = blockIdx.z;
    int b = z / NS, sl = z - b * NS;
    int WC = W >> 2;
    int idx = blockIdx.x * 256 + threadIdx.x;
    int xc = idx % WC, y = idx / WC;
    int x0 = xc << 2;
    bool lz = (x0 == 0), rz = (x0 + 4 == W);
    int co0 = blockIdx.y * NCO;
    float acc[NCO][4];
    #pragma unroll
    for (int j = 0; j < NCO; j++)
        #pragma unroll
        for (int p = 0; p < 4; p++) acc[j][p] = 0.f;

    const float* ib = in + ((size_t)b * Ci + sl * CS) * H * W;
    for (int ci = 0; ci < CS; ci++) {
        const float* ic = ib + (size_t)ci * H * W;
        int cig = sl * CS + ci;
        float sa = 1.f, sb = 0.f;
        if (sta) {
            int chg = b * Ci + cig;
            double S = sta[2 * chg], S2 = sta[2 * chg + 1];
            double n = (double)H * W;
            double md = S / n;
            double vr = S2 / n - md * md;
            float inv = rsqrtf((float)(vr < 0.0 ? 0.0 : vr) + EPS);
            sa = 1.f + 2.f * inv;
            sb = -2.f * (float)md * inv;
        }
        float e[3][6];
        #pragma unroll
        for (int r = 0; r < 3; r++) {
            int yy = y + r - 1;
            float4 v = make_float4(0.f, 0.f, 0.f, 0.f);
            if (yy >= 0 && yy < H) {
                v = *(const float4*)(ic + (size_t)yy * W + x0);
                if (sta) {
                    v.x = fmaf(v.x, sa, sb); v.y = fmaf(v.y, sa, sb);
                    v.z = fmaf(v.z, sa, sb); v.w = fmaf(v.w, sa, sb);
                }
            }
            float lf = __shfl_up(v.w, 1);
            float rt = __shfl_down(v.x, 1);
            e[r][0] = lz ? 0.f : lf;
            e[r][1] = v.x; e[r][2] = v.y; e[r][3] = v.z; e[r][4] = v.w;
            e[r][5] = rz ? 0.f : rt;
        }
        #pragma unroll
        for (int j = 0; j < NCO; j++) {
            const float* wj = w + ((size_t)(co0 + j) * Ci + cig) * 9;
            #pragma unroll
            for (int r = 0; r < 3; r++) {
                float w0 = wj[3 * r], w1 = wj[3 * r + 1], w2 = wj[3 * r + 2];
                #pragma unroll
                for (int p = 0; p < 4; p++)
                    acc[j][p] = fmaf(e[r][p], w0,
                                fmaf(e[r][p + 1], w1,
                                fmaf(e[r][p + 2], w2, acc[j][p])));
            }
        }
    }
    size_t HW = (size_t)H * W;
    #pragma unroll
    for (int j = 0; j < NCO; j++) {
        float bb = bias ? bias[co0 + j] : 0.f;
        float4 o = make_float4(acc[j][0] + bb, acc[j][1] + bb,
                               acc[j][2] + bb, acc[j][3] + bb);
        float* op = outp + (size_t)sl * SS
                  + ((size_t)b * Co + co0 + j) * HW + (size_t)y * W + x0;
        *(float4*)op = o;
    }
}

// ================= reduce partials (+bias, optional residual) ==================
__global__ __launch_bounds__(256) void reduce_k(const float* __restrict__ part,
    const float* __restrict__ bias, const float* res, float* out,
    int HW, int Co, int NS, size_t SS)
{
    reduce_body(blockIdx.x, part, bias, res, out, HW, Co, NS, SS);
}

// ====== PacConvT stage B: scatter/gather on bf16 Gin + fused f64 stats =========
template<int NCO>
__global__ __launch_bounds__(256) void pacsc_k(const ushort* __restrict__ Gin,
    const float* __restrict__ K, const float* __restrict__ bias,
    float* __restrict__ out, double* __restrict__ sta,
    int Cout, int Hi, int Wi, size_t gstride)
{
    int b = blockIdx.z;
    int H = Hi << 1, W = Wi << 1;
    int HW = H * W, HWi = Hi * Wi, WC = W >> 2;
    int idx = blockIdx.x * 256 + threadIdx.x;
    int half = (H >> 1) * WC;
    int py = (idx >= half) ? 1 : 0;
    int r = idx - py * half;
    int ry = r / WC;
    int y = 2 * ry + py;
    int x0 = (r - ry * WC) << 2;
    int yi = y >> 1, xi0 = x0 >> 1;
    int co0 = blockIdx.y * NCO;
    const ushort* G  = Gin + (size_t)b * gstride;
    const float* Kb = K + (size_t)b * 9 * HW;
    float* ob = out + (size_t)b * Cout * HW;
    size_t krow = (size_t)y * W + x0;
    bool vok = (xi0 + 2 < Wi);

    double ts[NCO], ts2[NCO];
    #pragma unroll
    for (int j = 0; j < NCO; j++) { ts[j] = 0.0; ts2[j] = 0.0; }

    if (py == 0) {
        float k4a = Kb[(size_t)4 * HW + krow],     k4b = Kb[(size_t)4 * HW + krow + 2];
        float k3a = Kb[(size_t)3 * HW + krow + 1], k3b = Kb[(size_t)3 * HW + krow + 3];
        float k5a = Kb[(size_t)5 * HW + krow + 1], k5b = Kb[(size_t)5 * HW + krow + 3];
        #pragma unroll
        for (int j = 0; j < NCO; j++) {
            int co = co0 + j;
            size_t rowb = (size_t)yi * Wi + xi0;
            const ushort* g3 = G + (size_t)(3 * Cout + co) * HWi + rowb;
            const ushort* g4 = G + (size_t)(4 * Cout + co) * HWi + rowb;
            const ushort* g5 = G + (size_t)(5 * Cout + co) * HWi + rowb;
            float bb = bias[co];
            float g5b = vok ? b2f(g5[2]) : 0.f;
            float o0 = fmaf(k4a, b2f(g4[0]), bb);
            float o1 = fmaf(k3a, b2f(g3[0]), fmaf(k5a, b2f(g5[1]), bb));
            float o2 = fmaf(k4b, b2f(g4[1]), bb);
            float o3 = fmaf(k3b, b2f(g3[1]), fmaf(k5b, g5b, bb));
            *(float4*)(ob + (size_t)co * HW + krow) = make_float4(o0, o1, o2, o3);
            ts[j]  += (double)o0 + o1 + o2 + o3;
            ts2[j] += (double)o0 * o0 + (double)o1 * o1
                    + (double)o2 * o2 + (double)o3 * o3;
        }
    } else {
        bool yok = (yi + 1 < Hi);
        float k1a = Kb[(size_t)1 * HW + krow],     k1b = Kb[(size_t)1 * HW + krow + 2];
        float k7a = Kb[(size_t)7 * HW + krow],     k7b = Kb[(size_t)7 * HW + krow + 2];
        float k0a = Kb[(size_t)0 * HW + krow + 1], k0b = Kb[(size_t)0 * HW + krow + 3];
        float k2a = Kb[(size_t)2 * HW + krow + 1], k2b = Kb[(size_t)2 * HW + krow + 3];
        float k6a = Kb[(size_t)6 * HW + krow + 1], k6b = Kb[(size_t)6 * HW + krow + 3];
        float k8a = Kb[(size_t)8 * HW + krow + 1], k8b = Kb[(size_t)8 * HW + krow + 3];
        #pragma unroll
        for (int j = 0; j < NCO; j++) {
            int co = co0 + j;
            size_t row0 = (size_t)yi * Wi + xi0;
            size_t row1 = (size_t)(yi + 1) * Wi + xi0;
            const ushort* g0 = G + (size_t)(0 * Cout + co) * HWi + row0;
            const ushort* g1 = G + (size_t)(1 * Cout + co) * HWi + row0;
            const ushort* g2 = G + (size_t)(2 * Cout + co) * HWi + row0;
            const ushort* g6 = G + (size_t)(6 * Cout + co) * HWi + row1;
            const ushort* g7 = G + (size_t)(7 * Cout + co) * HWi + row1;
            const ushort* g8 = G + (size_t)(8 * Cout + co) * HWi + row1;
            float bb = bias[co];
            float g2b = vok ? b2f(g2[2]) : 0.f;
            float g6a = yok ? b2f(g6[0]) : 0.f, g6b = yok ? b2f(g6[1]) : 0.f;
            float g7a = yok ? b2f(g7[0]) : 0.f, g7b = yok ? b2f(g7[1]) : 0.f;
            float g8a = yok ? b2f(g8[1]) : 0.f;
            float g8b = (yok && vok) ? b2f(g8[2]) : 0.f;
            float o0 = fmaf(k1a, b2f(g1[0]), fmaf(k7a, g7a, bb));
            float o1 = fmaf(k0a, b2f(g0[0]), fmaf(k2a, b2f(g2[1]),
                       fmaf(k6a, g6a, fmaf(k8a, g8a, bb))));
            float o2 = fmaf(k1b, b2f(g1[1]), fmaf(k7b, g7b, bb));
            float o3 = fmaf(k0b, b2f(g0[1]), fmaf(k2b, g2b,
                       fmaf(k6b, g6b, fmaf(k8b, g8b, bb))));
            *(float4*)(ob + (size_t)co * HW + krow) = make_float4(o0, o1, o2, o3);
            ts[j]  += (double)o0 + o1 + o2 + o3;
            ts2[j] += (double)o0 * o0 + (double)o1 * o1
                    + (double)o2 * o2 + (double)o3 * o3;
        }
    }

    // block-reduce Σ/Σ² per co, one pair of f64 atomics per co per block
    __shared__ double sred[8];
    int l = threadIdx.x & 63, wv = threadIdx.x >> 6;
    #pragma unroll
    for (int j = 0; j < NCO; j++) {
        double s = ts[j], s2 = ts2[j];
        for (int off = 32; off > 0; off >>= 1) {
            s  += __shfl_down(s, off);
            s2 += __shfl_down(s2, off);
        }
        if (l == 0) { sred[wv] = s; sred[4 + wv] = s2; }
        __syncthreads();
        if (threadIdx.x == 0) {
            double S  = sred[0] + sred[1] + sred[2] + sred[3];
            double S2 = sred[4] + sred[5] + sred[6] + sred[7];
            int co = co0 + j;
            atomicAdd(&sta[(size_t)(b * Cout + co) * 2],     S);
            atomicAdd(&sta[(size_t)(b * Cout + co) * 2 + 1], S2);
        }
        __syncthreads();
    }
}

// ==============================================================================
extern "C" void kernel_launch(void* const* d_in, const int* in_sizes, int n_in,
                              void* d_out, int out_size, void* d_ws, size_t ws_size,
                              hipStream_t stream)
{
    const float* x   = (const float*)d_in[0];   // (2,256,64,64)
    const float* ef2 = (const float*)d_in[1];   // (2,64,128,128)
    const float* ef1 = (const float*)d_in[2];   // (2,32,256,256)
    const float* Wd  = (const float*)d_in[3];
    const float* bd  = (const float*)d_in[4];
    const float* Wm  = (const float*)d_in[5];
    const float* bm  = (const float*)d_in[6];
    const float* Wa2 = (const float*)d_in[7];
    const float* ba2 = (const float*)d_in[8];
    const float* Wa1 = (const float*)d_in[9];
    const float* ba1 = (const float*)d_in[10];
    const float* W16 = (const float*)d_in[11];
    const float* b16 = (const float*)d_in[12];
    const float* W20 = (const float*)d_in[13];
    const float* b20 = (const float*)d_in[14];
    const float* W24 = (const float*)d_in[15];
    const float* b24 = (const float*)d_in[16];
    float* out = (float*)d_out;                 // (2,3,256,256)

    // ---- linear no-alias workspace layout (floats); ~205 MB of 256 MiB ----
    float* P = (float*)d_ws;
    size_t o = 0;
    auto take = [&](size_t n) { float* p = P + o; o += n; return p; };
    ushort* padDb  = (ushort*)take(1115136);   // 2x66x66x256 bf16
    ushort* wbD    = (ushort*)take(147456);
    float*  Pd     = take(8388608);            // conv_down partials NS=8
    float*  x1     = take(1048576);
    ushort* x2b    = (ushort*)take(524288);
    ushort* padA2b = (ushort*)take(1081600);   // 2x130x130x64
    ushort* wbA2b  = (ushort*)take(36864);
    ushort* g2     = (ushort*)take(2097152);   // bf16 full (2,128,128,128)
    float*  PK2    = take(2359296);            // K2 partials NS=8
    float*  K2     = take(294912);
    ushort* Gin1   = (ushort*)take(2359296);   // bf16 2x576x4096
    float*  x3     = take(2097152);
    ushort* x3b    = (ushort*)take(1048576);
    ushort* padA1b = (ushort*)take(2130048);   // 2x258x258x32
    ushort* wbA1b  = (ushort*)take(9216);
    ushort* g1     = (ushort*)take(4194304);   // bf16 full (2,64,256,256)
    float*  PK1    = take(4718592);            // K1 partials NS=4
    float*  K1     = take(1179648);
    ushort* Gin2   = (ushort*)take(4718592);   // bf16 2x288x16384
    float*  x5     = take(4194304);
    float*  Pf     = take(1572864);            // final conv partials NS=4
    ushort* wT1b   = (ushort*)take(36864);
    ushort* wT2b   = (ushort*)take(9216);
    float*  ST     = take(1024);               // f32 stats for x (istat path)
    double* STA    = (double*)take(768);       // 384 f64: [0..255] x3, [256..383] x5
    float* st0 = ST;

    // L0: wprep | istat(x) | pad(ef2) | pad(ef1)           [8660 blocks]
    pro_k<<<dim3(8660), dim3(256), 0, stream>>>(
        x, ef2, ef1, W16, W20, Wd, Wa2, Wa1,
        wT1b, wT2b, wbD, wbA2b, wbA1b, st0, padA2b, padA1b);

    // L1: adj_lv2 -> g2(bf16) | adj_lv1 -> g1(bf16) | ipad(x)  [5250 blocks]
    l1_k<<<dim3(5250), dim3(256), 0, stream>>>(
        x, st0, padDb, padA2b, wbA2b, ba2, g2, padA1b, wbA1b, ba1, g1);

    // L2: packK1 NS=4 | packK2 NS=8 | conv_down NS=8 -> Pd  [2816 blocks]
    l2_k<<<dim3(2816), dim3(256), 0, stream>>>(
        padDb, wbD, Pd, g1, PK1, g2, PK2);

    // L3: zero STA | reduce(Pd)+bias -> x1 | expcomb K1/K2  [2464 blocks]
    l3_k<<<dim3(2464), dim3(256), 0, stream>>>(Pd, bd, x1, PK1, K1, PK2, K2, STA);

    // fused 1x1: full-K + residual + bias -> x2b bf16 NHWC [256 blocks]
    conv1x1f_k<<<dim3(4, 32, 2), dim3(256), 0, stream>>>(x1, Wm, bm, x2b);

    // PacConvT #1: full-K GEMM (N=576, K=128) -> Gin1(bf16); scatter+stats -> x3
    mg2f_k<128, 1, 4, 4, 1><<<dim3(32, 18, 2), dim3(256), 0, stream>>>(
        x2b, wT1b, nullptr, Gin1, 0, 0, 1, (size_t)0,
        (size_t)524288, (size_t)2359296, 4096);
    pacsc_k<2><<<dim3(16, 32, 2), dim3(256), 0, stream>>>(
        Gin1, K2, b16, x3, STA, 64, 64, 64, (size_t)2359296);

    // double inorm+res fused into bf16-NHWC stage (stats from pacsc atomics)
    iapad_k<<<dim3(2048), dim3(256), 0, stream>>>(x3, STA, x3b, 16384, 64);

    // PacConvT #2: full-K GEMM (N=288, K=64) -> Gin2(bf16); scatter+stats -> x5
    mg2f_k<64, 1, 2, 2, 1><<<dim3(128, 9, 2), dim3(256), 0, stream>>>(
        x3b, wT2b, nullptr, Gin2, 0, 0, 1, (size_t)0,
        (size_t)1048576, (size_t)4718592, 16384);
    pacsc_k<2><<<dim3(64, 16, 2), dim3(256), 0, stream>>>(
        Gin2, K1, b20, x5, STA + 256, 32, 128, 128, (size_t)4718592);

    // final 32->3 @256x256 fp32 with fused x+2*inorm(x): NS=4 -> Pf; reduce -> out
    conv3x3_d<3><<<dim3(64, 1, 8), dim3(256), 0, stream>>>(
        x5, W24, nullptr, Pf, STA + 256, 32, 8, 256, 256, 3, 4, (size_t)393216);
    reduce_k<<<dim3(384), dim3(256), 0, stream>>>(Pf, b24, nullptr, out, 65536, 3, 4, 393216);
}